// Round 4
// baseline (352.628 us; speedup 1.0000x reference)
//
#include <hip/hip_runtime.h>
#include <math.h>

// Problem constants
constexpr int N_TOKENS = 8192;
constexpr int D_MODEL  = 4096;
constexpr int N_EXP    = 256;

// Fused one-shot GEMM: 32 tokens x 256 experts per block, no split-K.
constexpr int BM = 32;              // tokens per block
constexpr int BK = 32;              // K per chunk (= MFMA K)
constexpr int NC = D_MODEL / BK;    // 128 chunks

// ws B layout: [chunk c][plane hi/lo][256 exp x 32 k, XOR-swizzled granules]
constexpr int WPL = N_EXP * BK;     // 8192 ushorts per plane (16 KB)
constexpr int WCH = 2 * WPL;        // 16384 ushorts per chunk (32 KB)

// LDS layout (ushorts):
//   [0, 12288)        A fp32, 6 stages x 4096 B (32 tok x 32 k, source-swizzled)
//   [12288, 77824)    B bf16 hi/lo, 4 stages x 32768 B (verbatim wsB chunk image)
constexpr int NB = 4;                   // B stages (prefetch depth 3)
constexpr int NA = 6;                   // A stages (prefetch distance 4)
constexpr int A_ST_F = 1024;            // floats per A stage
constexpr int A_ST_U = 2048;            // ushorts per A stage
constexpr int BB_USH = NA * A_ST_U;     // 12288: ushort offset of B region
constexpr int B_ST_U = WCH;             // 16384 ushorts per B stage
constexpr size_t LDS_BYTES = (size_t)(BB_USH + NB * B_ST_U) * sizeof(unsigned short); // 155648 (152 KB)

constexpr size_t WS_NEED = (size_t)NC * WCH * sizeof(unsigned short);  // 4 MB

typedef __attribute__((ext_vector_type(8))) short short8;
typedef __attribute__((ext_vector_type(4))) float f32x4;
typedef unsigned int u32;
typedef const __attribute__((address_space(1))) u32* gas_ptr;
typedef __attribute__((address_space(3))) u32* las_ptr;

static __device__ __forceinline__ unsigned short f2bf(float x) {
    union { float f; unsigned u; } v; v.f = x;
    unsigned r = v.u + 0x7fffu + ((v.u >> 16) & 1u);   // RNE
    return (unsigned short)(r >> 16);
}
static __device__ __forceinline__ float bf2f(unsigned short s) {
    union { unsigned u; float f; } v; v.u = ((unsigned)s) << 16;
    return v.f;
}

// Split 8 fp32 -> bf16 hi (truncate) + bf16 lo (RNE of residual), packed pairs.
static __device__ __forceinline__ void split8(const float4 x0, const float4 x1,
                                              short8& hi, short8& lo) {
    const float xs[8] = {x0.x, x0.y, x0.z, x0.w, x1.x, x1.y, x1.z, x1.w};
    union { u32 u[4]; short8 v; } Hh, Ll;
    #pragma unroll
    for (int p = 0; p < 4; ++p) {
        const u32 u0 = __float_as_uint(xs[2*p]);
        const u32 u1 = __float_as_uint(xs[2*p + 1]);
        Hh.u[p] = (u0 >> 16) | (u1 & 0xffff0000u);
        const float r0 = xs[2*p]     - __uint_as_float(u0 & 0xffff0000u);
        const float r1 = xs[2*p + 1] - __uint_as_float(u1 & 0xffff0000u);
        const u32 b0 = __float_as_uint(r0);
        const u32 b1 = __float_as_uint(r1);
        Ll.u[p] = ((b0 + 0x7fffu + ((b0 >> 16) & 1u)) >> 16) |
                  ((b1 + 0x7fffu + ((b1 >> 16) & 1u)) & 0xffff0000u);
    }
    hi = Hh.v; lo = Ll.v;
}

// ---- W fp32 -> bf16 hi/lo, chunk-major + XOR-swizzled for global_load_lds ----
__global__ __launch_bounds__(256) void convert_w(
    const float* __restrict__ W, unsigned short* __restrict__ wsB)
{
    const int c    = blockIdx.x >> 2;           // chunk
    const int q    = blockIdx.x & 3;            // expert quarter
    const int t    = threadIdx.x;
    const int e    = q * 64 + (t >> 2);
    const int slot = t & 3;                     // physical 16B granule in row
    const int kq   = slot ^ ((e >> 1) & 3);     // logical k-granule (8 ushorts)

    const float* src = W + (size_t)e * D_MODEL + c * BK + kq * 8;
    const float4 x0 = *(const float4*)src;
    const float4 x1 = *(const float4*)(src + 4);
    const float xs[8] = {x0.x, x0.y, x0.z, x0.w, x1.x, x1.y, x1.z, x1.w};
    short8 vh, vl;
    #pragma unroll
    for (int j = 0; j < 8; ++j) {
        const unsigned short h = f2bf(xs[j]);
        vh[j] = (short)h;
        vl[j] = (short)f2bf(xs[j] - bf2f(h));
    }
    unsigned short* dst = wsB + (size_t)c * WCH + e * 32 + slot * 8;
    *(short8*)dst         = vh;
    *(short8*)(dst + WPL) = vl;
}

// ---- fused GEMM (bf16x3) + sigmoid + group-top2 + coalesced logits ----
// 8 waves x 32 experts. All staging via global_load_lds. Per-iter VMEM groups:
// waves 0-3 issue [B x4, A x1] = 5 ops, waves 4-7 [B x4]. Counted waits
// vmcnt(15)/vmcnt(12) keep 3 iterations in flight; barriers drain lgkm only.
// B is wave-private. A (cross-wave) is drained by its issuer one barrier
// before the consuming iteration. Per-XCD chunk phase de-correlates the L2
// hot set (8 XCDs read 8 different 32KB chunks at any time).
__global__ __launch_bounds__(512, 1) void gate_fused(
    const float* __restrict__ H, const unsigned short* __restrict__ wsB,
    float* __restrict__ logits, float* __restrict__ out_idx, float* __restrict__ out_w)
{
    extern __shared__ unsigned short lds[];

    const int t      = threadIdx.x;
    const int L      = t & 63;
    const int w      = t >> 6;          // wave 0..7: experts [w*32, w*32+32)
    const int lane16 = L & 15;
    const int g4     = L >> 4;          // k-granule for frag reads
    const int tok0   = blockIdx.x * BM;
    const int phase  = (blockIdx.x & 7) << 4;   // per-XCD chunk rotation

    // A staging map (threads 0..255 only): thread t -> row t>>3, phys slot
    // (gp=(t>>1)&3, hp=t&1); source swizzled so LDS image carries
    // logical (gl = gp ^ ((row>>1)&3), hl = hp ^ (row&1)).
    const int tokA = t >> 3;
    const int gl   = ((t >> 1) & 3) ^ ((tokA >> 1) & 3);
    const int hl   = (t & 1) ^ (tokA & 1);
    const float* srcA = H + (size_t)(tok0 + (tokA & 31)) * D_MODEL + gl * 8 + hl * 4;

    f32x4 acc[2][2];
    #pragma unroll
    for (int mi = 0; mi < 2; ++mi)
        #pragma unroll
        for (int ni = 0; ni < 2; ++ni) acc[mi][ni] = (f32x4)0.0f;

    auto dmaB = [&](int pc, int s) {
        const unsigned short* src = wsB + (size_t)pc * WCH;
        unsigned short* dst = lds + BB_USH + s * B_ST_U;
        #pragma unroll
        for (int p = 0; p < 2; ++p)
            #pragma unroll
            for (int i = 0; i < 2; ++i) {
                const int o = p * WPL + (w * 2 + i) * 512;   // ushort offset
                __builtin_amdgcn_global_load_lds(
                    (gas_ptr)(const void*)(src + o + L * 8),
                    (las_ptr)(void*)(dst + o), 16, 0, 0);
            }
    };

    auto dmaA = [&](int pc, int s) {       // only called for t < 256
        __builtin_amdgcn_global_load_lds(
            (gas_ptr)(const void*)(srcA + (size_t)pc * BK),
            (las_ptr)(void*)(lds + s * A_ST_U + w * 512), 16, 0, 0);
    };

    auto compute = [&](int sB, int sA) {
        const float*          Af = (const float*)(const void*)lds + sA * A_ST_F;
        const unsigned short* Bh = lds + BB_USH + sB * B_ST_U;
        const unsigned short* Bl = Bh + WPL;
        short8 ah[2], al[2];
        #pragma unroll
        for (int mi = 0; mi < 2; ++mi) {
            const int row = mi * 16 + lane16;
            const int gp  = g4 ^ ((row >> 1) & 3);
            const float* ap = Af + row * 32 + gp * 8;
            const int swp = (row & 1) << 2;
            const float4 x0 = *(const float4*)(ap + swp);        // logical k 0..3
            const float4 x1 = *(const float4*)(ap + (swp ^ 4));  // logical k 4..7
            split8(x0, x1, ah[mi], al[mi]);
        }
        __builtin_amdgcn_s_setprio(1);
        #pragma unroll
        for (int ni = 0; ni < 2; ++ni) {
            const int e   = w * 32 + ni * 16 + lane16;
            const int off = e * 32 + ((g4 ^ ((e >> 1) & 3)) << 3);
            const short8 bh = *(const short8*)(Bh + off);
            const short8 bl = *(const short8*)(Bl + off);
            #pragma unroll
            for (int mi = 0; mi < 2; ++mi) {
                acc[mi][ni] = __builtin_amdgcn_mfma_f32_16x16x32_bf16(ah[mi], bh, acc[mi][ni], 0, 0, 0);
                acc[mi][ni] = __builtin_amdgcn_mfma_f32_16x16x32_bf16(ah[mi], bl, acc[mi][ni], 0, 0, 0);
                acc[mi][ni] = __builtin_amdgcn_mfma_f32_16x16x32_bf16(al[mi], bh, acc[mi][ni], 0, 0, 0);
            }
        }
        __builtin_amdgcn_s_setprio(0);
    };

    auto pch = [&](int c) { return (c + phase) & (NC - 1); };

    // Prologue: g(-3)=[B(0),A(0),A(1)] (6/4 ops), g(-2)=[B(1),A(2)] (5/4),
    // g(-1)=[B(2),A(3)] (5/4). Drain g(-3): vmcnt(10)/vmcnt(8); barrier
    // publishes A(0),A(1).
    dmaB(pch(0), 0);
    if (t < 256) { dmaA(pch(0), 0); dmaA(pch(1), 1); }
    __builtin_amdgcn_sched_barrier(0);
    dmaB(pch(1), 1);
    if (t < 256) dmaA(pch(2), 2);
    __builtin_amdgcn_sched_barrier(0);
    dmaB(pch(2), 2);
    if (t < 256) dmaA(pch(3), 3);
    __builtin_amdgcn_sched_barrier(0);
    if (t < 256) { asm volatile("s_waitcnt vmcnt(10)" ::: "memory"); }
    else         { asm volatile("s_waitcnt vmcnt(8)"  ::: "memory"); }
    __builtin_amdgcn_sched_barrier(0);
    __builtin_amdgcn_s_barrier();

    // Steady: iter c issues g(c)=[B(c+3) -> stage (c+3)&3, A(c+4) -> stage
    // (c+4)%6]; wait drains g(c-3) = {B(c) (wave-private, read now), A(c+1)
    // (published by this iter's barrier, read next iter)}. Tail iters issue
    // clamped redundant loads so each group keeps its exact op count.
    int sAr = 0, sAw = 4;
    for (int c = 0; c < NC; ++c) {
        const int cB = (c + 3 < NC) ? c + 3 : NC - 1;
        const int cA = (c + 4 < NC) ? c + 4 : NC - 1;
        dmaB(pch(cB), (c + 3) & 3);
        if (t < 256) dmaA(pch(cA), sAw);
        __builtin_amdgcn_sched_barrier(0);
        if (t < 256) { asm volatile("s_waitcnt vmcnt(15)" ::: "memory"); }
        else         { asm volatile("s_waitcnt vmcnt(12)" ::: "memory"); }
        __builtin_amdgcn_sched_barrier(0);
        compute(c & 3, sAr);
        asm volatile("s_waitcnt lgkmcnt(0)" ::: "memory");
        __builtin_amdgcn_s_barrier();
        if (++sAr == NA) sAr = 0;
        if (++sAw == NA) sAw = 0;
    }
    // Deterministic full drain (clamped tail DMAs) before LDS re-aliasing.
    asm volatile("s_waitcnt vmcnt(0) lgkmcnt(0)" ::: "memory");
    __builtin_amdgcn_sched_barrier(0);
    __builtin_amdgcn_s_barrier();

    // ---- epilogue: LDS-transpose bounce, coalesced logits, fused topk ----
    float* Lt = (float*)lds;            // [32][256] fp32 = 32 KB (aliases stages)
    #pragma unroll
    for (int mi = 0; mi < 2; ++mi)
        #pragma unroll
        for (int ni = 0; ni < 2; ++ni)
            #pragma unroll
            for (int r = 0; r < 4; ++r) {
                const int tok = mi * 16 + g4 * 4 + r;       // C/D: row = quad*4+reg
                const int col = w * 32 + ni * 16 + lane16;  // C/D: col = lane&15
                Lt[tok * N_EXP + col] = acc[mi][ni][r];
            }
    __syncthreads();

    // coalesced logits store: 8192 floats = 2048 float4, 4 per thread
    float4*       Lg  = (float4*)(logits + (size_t)tok0 * N_EXP);
    const float4* Lt4 = (const float4*)Lt;
    #pragma unroll
    for (int i = 0; i < 4; ++i) Lg[i * 512 + t] = Lt4[i * 512 + t];

    // topk: wave w handles local tokens w*4 .. w*4+3
    for (int it = 0; it < 4; ++it) {
        const int tk = w * 4 + it;
        const float4 x = ((const float4*)(Lt + tk * N_EXP))[L];
        float sc[4];
        sc[0] = 1.0f / (1.0f + expf(-x.x));
        sc[1] = 1.0f / (1.0f + expf(-x.y));
        sc[2] = 1.0f / (1.0f + expf(-x.z));
        sc[3] = 1.0f / (1.0f + expf(-x.w));

        float v1 = -1.0f, v2 = -1.0f;
        int   i1 = 0,     i2 = 0;
        #pragma unroll
        for (int j = 0; j < 4; ++j) {
            const int idx = L * 4 + j;
            if (sc[j] > v1)      { v2 = v1; i2 = i1; v1 = sc[j]; i1 = idx; }
            else if (sc[j] > v2) { v2 = sc[j]; i2 = idx; }
        }
        // butterfly merge across each 16-lane group (= 64-expert group)
        #pragma unroll
        for (int offx = 1; offx < 16; offx <<= 1) {
            const float ov1 = __shfl_xor(v1, offx);
            const int   oi1 = __shfl_xor(i1, offx);
            const float ov2 = __shfl_xor(v2, offx);
            const int   oi2 = __shfl_xor(i2, offx);
            const bool o1_beats_m1 = (ov1 > v1) || (ov1 == v1 && oi1 < i1);
            if (o1_beats_m1) {
                const bool m1_beats_o2 = (v1 > ov2) || (v1 == ov2 && i1 < oi2);
                const float nv2 = m1_beats_o2 ? v1 : ov2;
                const int   ni2 = m1_beats_o2 ? i1 : oi2;
                v1 = ov1; i1 = oi1; v2 = nv2; i2 = ni2;
            } else {
                const bool o1_beats_m2 = (ov1 > v2) || (ov1 == v2 && oi1 < i2);
                v2 = o1_beats_m2 ? ov1 : v2;
                i2 = o1_beats_m2 ? oi1 : i2;
            }
        }
        float sum = 0.0f;
        #pragma unroll
        for (int g = 0; g < 4; ++g)
            sum += __shfl(v1, g * 16) + __shfl(v2, g * 16);
        const int   src = ((L >> 1) & 3) * 16;
        const float mv1 = __shfl(v1, src);
        const float mv2 = __shfl(v2, src);
        const int   mi1 = __shfl(i1, src);
        const int   mi2 = __shfl(i2, src);
        if (L < 8) {
            const float myv = (L & 1) ? mv2 : mv1;
            const int   myi = (L & 1) ? mi2 : mi1;
            out_idx[(size_t)(tok0 + tk) * 8 + L] = (float)myi;
            out_w  [(size_t)(tok0 + tk) * 8 + L] = myv * (2.5f / (sum + 1e-10f));
        }
    }
}

// ---------------- fallback (ws too small): fp32 VALU path ----------------
constexpr int FBM = 32;
constexpr int FBK = 16;
constexpr int FNC = D_MODEL / FBK;

__global__ __launch_bounds__(256) void gate_gemm_f32(
    const float* __restrict__ H, const float* __restrict__ W,
    float* __restrict__ logits)
{
    __shared__ float As[2][FBK][FBM + 4];
    __shared__ float Bs[2][FBK][N_EXP + 1];
    const int t = threadIdx.x, tx = t & 31, ty = t >> 5;
    const int tok0 = blockIdx.x * FBM, tokA = t >> 2, kqA = t & 3;
    float4 pa, pb[4];
    float acc[4][8];
    #pragma unroll
    for (int i = 0; i < 4; ++i)
        #pragma unroll
        for (int j = 0; j < 8; ++j) acc[i][j] = 0.0f;
    auto issue_loads = [&](int kc) {
        if (t < 128) pa = *(const float4*)(H + (size_t)(tok0 + tokA) * D_MODEL + kc + kqA * 4);
        #pragma unroll
        for (int j = 0; j < 4; ++j) {
            const int flat = t + 256 * j, e = flat >> 2, kq = flat & 3;
            pb[j] = *(const float4*)(W + (size_t)e * D_MODEL + kc + kq * 4);
        }
    };
    auto write_lds = [&](int buf) {
        if (t < 128) {
            As[buf][kqA * 4 + 0][tokA] = pa.x; As[buf][kqA * 4 + 1][tokA] = pa.y;
            As[buf][kqA * 4 + 2][tokA] = pa.z; As[buf][kqA * 4 + 3][tokA] = pa.w;
        }
        #pragma unroll
        for (int j = 0; j < 4; ++j) {
            const int flat = t + 256 * j, e = flat >> 2, kq = flat & 3;
            Bs[buf][kq * 4 + 0][e] = pb[j].x; Bs[buf][kq * 4 + 1][e] = pb[j].y;
            Bs[buf][kq * 4 + 2][e] = pb[j].z; Bs[buf][kq * 4 + 3][e] = pb[j].w;
        }
    };
    issue_loads(0); write_lds(0); __syncthreads();
    for (int c = 0; c < FNC; ++c) {
        const int buf = c & 1;
        if (c + 1 < FNC) issue_loads((c + 1) * FBK);
        #pragma unroll
        for (int k = 0; k < FBK; ++k) {
            const float4 av = *(const float4*)&As[buf][k][ty * 4];
            const float a[4] = {av.x, av.y, av.z, av.w};
            float b[8];
            #pragma unroll
            for (int j = 0; j < 8; ++j) b[j] = Bs[buf][k][tx + 32 * j];
            #pragma unroll
            for (int i = 0; i < 4; ++i)
                #pragma unroll
                for (int j = 0; j < 8; ++j) acc[i][j] = fmaf(a[i], b[j], acc[i][j]);
        }
        if (c + 1 < FNC) write_lds(buf ^ 1);
        __syncthreads();
    }
    #pragma unroll
    for (int i = 0; i < 4; ++i) {
        const size_t row = (size_t)(tok0 + ty * 4 + i) * N_EXP;
        #pragma unroll
        for (int j = 0; j < 8; ++j) logits[row + tx + 32 * j] = acc[i][j];
    }
}

__global__ __launch_bounds__(256) void topk_only(
    const float* __restrict__ logits,
    float* __restrict__ out_idx, float* __restrict__ out_w)
{
    const int token = blockIdx.x * 4 + (threadIdx.x >> 6);
    const int lane  = threadIdx.x & 63;
    const float4 x = *(const float4*)(logits + (size_t)token * N_EXP + lane * 4);
    float sc[4];
    sc[0] = 1.0f / (1.0f + expf(-x.x)); sc[1] = 1.0f / (1.0f + expf(-x.y));
    sc[2] = 1.0f / (1.0f + expf(-x.z)); sc[3] = 1.0f / (1.0f + expf(-x.w));
    float v1 = -1.0f, v2 = -1.0f; int i1 = 0, i2 = 0;
    #pragma unroll
    for (int j = 0; j < 4; ++j) {
        const int idx = lane * 4 + j;
        if (sc[j] > v1)      { v2 = v1; i2 = i1; v1 = sc[j]; i1 = idx; }
        else if (sc[j] > v2) { v2 = sc[j]; i2 = idx; }
    }
    #pragma unroll
    for (int offx = 1; offx < 16; offx <<= 1) {
        const float ov1 = __shfl_xor(v1, offx); const int oi1 = __shfl_xor(i1, offx);
        const float ov2 = __shfl_xor(v2, offx); const int oi2 = __shfl_xor(i2, offx);
        const bool o1_beats_m1 = (ov1 > v1) || (ov1 == v1 && oi1 < i1);
        if (o1_beats_m1) {
            const bool m1_beats_o2 = (v1 > ov2) || (v1 == ov2 && i1 < oi2);
            const float nv2 = m1_beats_o2 ? v1 : ov2;
            const int   ni2 = m1_beats_o2 ? i1 : oi2;
            v1 = ov1; i1 = oi1; v2 = nv2; i2 = ni2;
        } else {
            const bool o1_beats_m2 = (ov1 > v2) || (ov1 == v2 && oi1 < i2);
            v2 = o1_beats_m2 ? ov1 : v2; i2 = o1_beats_m2 ? oi1 : i2;
        }
    }
    float sum = 0.0f;
    #pragma unroll
    for (int g = 0; g < 4; ++g) sum += __shfl(v1, g * 16) + __shfl(v2, g * 16);
    const int src = ((lane >> 1) & 3) * 16;
    const float mv1 = __shfl(v1, src), mv2 = __shfl(v2, src);
    const int   mi1 = __shfl(i1, src), mi2 = __shfl(i2, src);
    if (lane < 8) {
        const float myv = (lane & 1) ? mv2 : mv1;
        const int   myi = (lane & 1) ? mi2 : mi1;
        out_idx[(size_t)token * 8 + lane] = (float)myi;
        out_w  [(size_t)token * 8 + lane] = myv * (2.5f / (sum + 1e-10f));
    }
}

extern "C" void kernel_launch(void* const* d_in, const int* in_sizes, int n_in,
                              void* d_out, int out_size, void* d_ws, size_t ws_size,
                              hipStream_t stream) {
    const float* H = (const float*)d_in[0];   // hidden_states [8192, 4096]
    const float* W = (const float*)d_in[1];   // gate_w        [256, 4096]

    float* out     = (float*)d_out;
    float* out_idx = out;                           // 8192*8
    float* out_w   = out + (size_t)N_TOKENS * 8;    // 8192*8
    float* logits  = out + (size_t)N_TOKENS * 16;   // 8192*256

    if (ws_size >= WS_NEED) {
        unsigned short* wsB = (unsigned short*)d_ws;
        static bool attr_done = []() {
            hipFuncSetAttribute((const void*)gate_fused,
                                hipFuncAttributeMaxDynamicSharedMemorySize,
                                (int)LDS_BYTES);
            return true;
        }();
        (void)attr_done;
        convert_w<<<dim3(NC * 4), dim3(256), 0, stream>>>(W, wsB);
        gate_fused<<<dim3(N_TOKENS / BM), dim3(512), LDS_BYTES, stream>>>(
            H, wsB, logits, out_idx, out_w);
    } else {
        gate_gemm_f32<<<dim3(N_TOKENS / FBM), dim3(256), 0, stream>>>(H, W, logits);
        topk_only<<<dim3(N_TOKENS / 4), dim3(256), 0, stream>>>(logits, out_idx, out_w);
    }
}

// Round 5
// 292.485 us; speedup vs baseline: 1.2056x; 1.2056x over previous
//
#include <hip/hip_runtime.h>
#include <math.h>

// Problem constants
constexpr int N_TOKENS = 8192;
constexpr int D_MODEL  = 4096;
constexpr int N_EXP    = 256;

// Fused one-shot GEMM: 32 tokens x 256 experts per block, no split-K.
constexpr int BM = 32;              // tokens per block
constexpr int BK = 32;              // K per chunk (= MFMA K)
constexpr int NC = D_MODEL / BK;    // 128 chunks

// ws B layout: [chunk c][plane hi/lo][256 exp x 32 k, XOR-swizzled granules]
constexpr int WPL = N_EXP * BK;     // 8192 ushorts per plane (16 KB)
constexpr int WCH = 2 * WPL;        // 16384 ushorts per chunk (32 KB)

// LDS layout (ushorts):
//   [0, 12288)        A fp32, 6 stages x 4096 B (32 tok x 32 k, source-swizzled)
//   [12288, 77824)    B bf16 hi/lo, 4 stages x 32768 B (verbatim wsB chunk image)
constexpr int NB = 4;                   // B stages (prefetch depth 3)
constexpr int NA = 6;                   // A stages (prefetch distance 4)
constexpr int A_ST_F = 1024;            // floats per A stage
constexpr int A_ST_U = 2048;            // ushorts per A stage
constexpr int BB_USH = NA * A_ST_U;     // 12288: ushort offset of B region
constexpr int B_ST_U = WCH;             // 16384 ushorts per B stage
constexpr size_t LDS_BYTES = (size_t)(BB_USH + NB * B_ST_U) * sizeof(unsigned short); // 155648 (152 KB)

// LDS byte-offset constants for the asm read path
constexpr unsigned A_ST_BYTES = 4096;
constexpr unsigned B_BASE_BYTES = (unsigned)BB_USH * 2;   // 24576
constexpr unsigned B_ST_BYTES = 32768;
constexpr unsigned B_PLANE_BYTES = (unsigned)WPL * 2;     // 16384

constexpr size_t WS_NEED = (size_t)NC * WCH * sizeof(unsigned short);  // 4 MB

typedef __attribute__((ext_vector_type(8))) short short8;
typedef __attribute__((ext_vector_type(4))) float f32x4;
typedef unsigned int u32;
typedef const __attribute__((address_space(1))) u32* gas_ptr;
typedef __attribute__((address_space(3))) u32* las_ptr;

static __device__ __forceinline__ unsigned short f2bf(float x) {
    union { float f; unsigned u; } v; v.f = x;
    unsigned r = v.u + 0x7fffu + ((v.u >> 16) & 1u);   // RNE
    return (unsigned short)(r >> 16);
}
static __device__ __forceinline__ float bf2f(unsigned short s) {
    union { unsigned u; float f; } v; v.u = ((unsigned)s) << 16;
    return v.f;
}

// Opaque LDS reads: raw byte-offset ds_read_b128. Invisible to the compiler's
// memory model, so it cannot insert its own vmcnt(0) drain for the
// global_load_lds DMAs — ordering is ours via counted vmcnt + lgkmcnt +
// sched_barrier (rule #18).
static __device__ __forceinline__ short8 lds_read_s8(unsigned byte_off) {
    short8 r;
    asm volatile("ds_read_b128 %0, %1" : "=v"(r) : "v"(byte_off));
    return r;
}
static __device__ __forceinline__ f32x4 lds_read_f4(unsigned byte_off) {
    f32x4 r;
    asm volatile("ds_read_b128 %0, %1" : "=v"(r) : "v"(byte_off));
    return r;
}

// Split 8 fp32 -> bf16 hi (truncate) + bf16 lo (RNE of residual), packed pairs.
static __device__ __forceinline__ void split8(const f32x4 x0, const f32x4 x1,
                                              short8& hi, short8& lo) {
    const float xs[8] = {x0[0], x0[1], x0[2], x0[3], x1[0], x1[1], x1[2], x1[3]};
    union { u32 u[4]; short8 v; } Hh, Ll;
    #pragma unroll
    for (int p = 0; p < 4; ++p) {
        const u32 u0 = __float_as_uint(xs[2*p]);
        const u32 u1 = __float_as_uint(xs[2*p + 1]);
        Hh.u[p] = (u0 >> 16) | (u1 & 0xffff0000u);
        const float r0 = xs[2*p]     - __uint_as_float(u0 & 0xffff0000u);
        const float r1 = xs[2*p + 1] - __uint_as_float(u1 & 0xffff0000u);
        const u32 b0 = __float_as_uint(r0);
        const u32 b1 = __float_as_uint(r1);
        Ll.u[p] = ((b0 + 0x7fffu + ((b0 >> 16) & 1u)) >> 16) |
                  ((b1 + 0x7fffu + ((b1 >> 16) & 1u)) & 0xffff0000u);
    }
    hi = Hh.v; lo = Ll.v;
}

// ---- W fp32 -> bf16 hi/lo, chunk-major + XOR-swizzled for global_load_lds ----
__global__ __launch_bounds__(256) void convert_w(
    const float* __restrict__ W, unsigned short* __restrict__ wsB)
{
    const int c    = blockIdx.x >> 2;           // chunk
    const int q    = blockIdx.x & 3;            // expert quarter
    const int t    = threadIdx.x;
    const int e    = q * 64 + (t >> 2);
    const int slot = t & 3;                     // physical 16B granule in row
    const int kq   = slot ^ ((e >> 1) & 3);     // logical k-granule (8 ushorts)

    const float* src = W + (size_t)e * D_MODEL + c * BK + kq * 8;
    const float4 x0 = *(const float4*)src;
    const float4 x1 = *(const float4*)(src + 4);
    const float xs[8] = {x0.x, x0.y, x0.z, x0.w, x1.x, x1.y, x1.z, x1.w};
    short8 vh, vl;
    #pragma unroll
    for (int j = 0; j < 8; ++j) {
        const unsigned short h = f2bf(xs[j]);
        vh[j] = (short)h;
        vl[j] = (short)f2bf(xs[j] - bf2f(h));
    }
    unsigned short* dst = wsB + (size_t)c * WCH + e * 32 + slot * 8;
    *(short8*)dst         = vh;
    *(short8*)(dst + WPL) = vl;
}

// ---- fused GEMM (bf16x3) + sigmoid + group-top2 + coalesced logits ----
// 8 waves x 32 experts. All staging via global_load_lds; all hot-loop LDS
// reads via opaque inline-asm ds_read_b128 so the compiler cannot insert a
// vmcnt(0) drain. Counted waits vmcnt(15)/vmcnt(12) keep 3 iterations of
// loads in flight across barriers.
__global__ __launch_bounds__(512, 1) void gate_fused(
    const float* __restrict__ H, const unsigned short* __restrict__ wsB,
    float* __restrict__ logits, float* __restrict__ out_idx, float* __restrict__ out_w)
{
    extern __shared__ unsigned short lds[];

    const int t      = threadIdx.x;
    const int L      = t & 63;
    const int w      = t >> 6;          // wave 0..7: experts [w*32, w*32+32)
    const int lane16 = L & 15;
    const int g4     = L >> 4;          // k-granule for frag reads
    const int tok0   = blockIdx.x * BM;
    const int phase  = (blockIdx.x & 7) << 4;   // per-XCD chunk rotation

    // A staging map (threads 0..255 only): thread t -> row t>>3, phys slot
    // (gp=(t>>1)&3, hp=t&1); source swizzled so LDS image carries
    // logical (gl = gp ^ ((row>>1)&3), hl = hp ^ (row&1)).
    const int tokA = t >> 3;
    const int gl   = ((t >> 1) & 3) ^ ((tokA >> 1) & 3);
    const int hl   = (t & 1) ^ (tokA & 1);
    const float* srcA = H + (size_t)(tok0 + (tokA & 31)) * D_MODEL + gl * 8 + hl * 4;

    f32x4 acc[2][2];
    #pragma unroll
    for (int mi = 0; mi < 2; ++mi)
        #pragma unroll
        for (int ni = 0; ni < 2; ++ni) acc[mi][ni] = (f32x4)0.0f;

    auto dmaB = [&](int pc, int s) {
        const unsigned short* src = wsB + (size_t)pc * WCH;
        unsigned short* dst = lds + BB_USH + s * B_ST_U;
        #pragma unroll
        for (int p = 0; p < 2; ++p)
            #pragma unroll
            for (int i = 0; i < 2; ++i) {
                const int o = p * WPL + (w * 2 + i) * 512;   // ushort offset
                __builtin_amdgcn_global_load_lds(
                    (gas_ptr)(const void*)(src + o + L * 8),
                    (las_ptr)(void*)(dst + o), 16, 0, 0);
            }
    };

    auto dmaA = [&](int pc, int s) {       // only called for t < 256
        __builtin_amdgcn_global_load_lds(
            (gas_ptr)(const void*)(srcA + (size_t)pc * BK),
            (las_ptr)(void*)(lds + s * A_ST_U + w * 512), 16, 0, 0);
    };

    auto compute = [&](int sB, int sA) {
        const unsigned aBase = (unsigned)sA * A_ST_BYTES;
        const unsigned bBase = B_BASE_BYTES + (unsigned)sB * B_ST_BYTES;
        // Issue all 8 LDS reads (asm, lgkm-counted), then one wait.
        f32x4 x0[2], x1[2];
        #pragma unroll
        for (int mi = 0; mi < 2; ++mi) {
            const int row = mi * 16 + lane16;
            const int gp  = g4 ^ ((row >> 1) & 3);
            const int swp = (row & 1) << 2;
            const unsigned a0 = aBase + (unsigned)(row * 32 + gp * 8 + swp) * 4;
            const unsigned a1 = aBase + (unsigned)(row * 32 + gp * 8 + (swp ^ 4)) * 4;
            x0[mi] = lds_read_f4(a0);
            x1[mi] = lds_read_f4(a1);
        }
        short8 bh[2], bl[2];
        #pragma unroll
        for (int ni = 0; ni < 2; ++ni) {
            const int e = w * 32 + ni * 16 + lane16;
            const unsigned boff = (unsigned)(e * 32 + ((g4 ^ ((e >> 1) & 3)) << 3)) * 2;
            bh[ni] = lds_read_s8(bBase + boff);
            bl[ni] = lds_read_s8(bBase + B_PLANE_BYTES + boff);
        }
        asm volatile("s_waitcnt lgkmcnt(0)" ::: "memory");
        __builtin_amdgcn_sched_barrier(0);   // rule #18: nothing hoists above
        short8 ah[2], al[2];
        split8(x0[0], x1[0], ah[0], al[0]);
        split8(x0[1], x1[1], ah[1], al[1]);
        __builtin_amdgcn_s_setprio(1);
        #pragma unroll
        for (int ni = 0; ni < 2; ++ni)
            #pragma unroll
            for (int mi = 0; mi < 2; ++mi) {
                acc[mi][ni] = __builtin_amdgcn_mfma_f32_16x16x32_bf16(ah[mi], bh[ni], acc[mi][ni], 0, 0, 0);
                acc[mi][ni] = __builtin_amdgcn_mfma_f32_16x16x32_bf16(ah[mi], bl[ni], acc[mi][ni], 0, 0, 0);
                acc[mi][ni] = __builtin_amdgcn_mfma_f32_16x16x32_bf16(al[mi], bh[ni], acc[mi][ni], 0, 0, 0);
            }
        __builtin_amdgcn_s_setprio(0);
    };

    auto pch = [&](int c) { return (c + phase) & (NC - 1); };

    // Prologue: g(-3)=[B(0),A(0),A(1)] (6/4 ops), g(-2)=[B(1),A(2)] (5/4),
    // g(-1)=[B(2),A(3)] (5/4). Drain g(-3): vmcnt(10)/vmcnt(8); barrier
    // publishes A(0),A(1).
    dmaB(pch(0), 0);
    if (t < 256) { dmaA(pch(0), 0); dmaA(pch(1), 1); }
    __builtin_amdgcn_sched_barrier(0);
    dmaB(pch(1), 1);
    if (t < 256) dmaA(pch(2), 2);
    __builtin_amdgcn_sched_barrier(0);
    dmaB(pch(2), 2);
    if (t < 256) dmaA(pch(3), 3);
    __builtin_amdgcn_sched_barrier(0);
    if (t < 256) { asm volatile("s_waitcnt vmcnt(10)" ::: "memory"); }
    else         { asm volatile("s_waitcnt vmcnt(8)"  ::: "memory"); }
    __builtin_amdgcn_sched_barrier(0);
    __builtin_amdgcn_s_barrier();

    // Steady: iter c issues g(c)=[B(c+3) -> stage (c+3)&3, A(c+4) -> stage
    // (c+4)%6]; wait drains g(c-3) = {B(c) (wave-private, read now), A(c+1)
    // (published by this iter's barrier, read next iter)}. Tail iters issue
    // clamped redundant loads so each group keeps its exact op count.
    int sAr = 0, sAw = 4;
    for (int c = 0; c < NC; ++c) {
        const int cB = (c + 3 < NC) ? c + 3 : NC - 1;
        const int cA = (c + 4 < NC) ? c + 4 : NC - 1;
        dmaB(pch(cB), (c + 3) & 3);
        if (t < 256) dmaA(pch(cA), sAw);
        __builtin_amdgcn_sched_barrier(0);
        if (t < 256) { asm volatile("s_waitcnt vmcnt(15)" ::: "memory"); }
        else         { asm volatile("s_waitcnt vmcnt(12)" ::: "memory"); }
        __builtin_amdgcn_sched_barrier(0);
        compute(c & 3, sAr);
        asm volatile("s_waitcnt lgkmcnt(0)" ::: "memory");
        __builtin_amdgcn_s_barrier();
        if (++sAr == NA) sAr = 0;
        if (++sAw == NA) sAw = 0;
    }
    // Deterministic full drain (clamped tail DMAs) before LDS re-aliasing.
    asm volatile("s_waitcnt vmcnt(0) lgkmcnt(0)" ::: "memory");
    __builtin_amdgcn_sched_barrier(0);
    __builtin_amdgcn_s_barrier();

    // ---- epilogue: LDS-transpose bounce, coalesced logits, fused topk ----
    float* Lt = (float*)lds;            // [32][256] fp32 = 32 KB (aliases stages)
    #pragma unroll
    for (int mi = 0; mi < 2; ++mi)
        #pragma unroll
        for (int ni = 0; ni < 2; ++ni)
            #pragma unroll
            for (int r = 0; r < 4; ++r) {
                const int tok = mi * 16 + g4 * 4 + r;       // C/D: row = quad*4+reg
                const int col = w * 32 + ni * 16 + lane16;  // C/D: col = lane&15
                Lt[tok * N_EXP + col] = acc[mi][ni][r];
            }
    __syncthreads();

    // coalesced logits store: 8192 floats = 2048 float4, 4 per thread
    float4*       Lg  = (float4*)(logits + (size_t)tok0 * N_EXP);
    const float4* Lt4 = (const float4*)Lt;
    #pragma unroll
    for (int i = 0; i < 4; ++i) Lg[i * 512 + t] = Lt4[i * 512 + t];

    // topk: wave w handles local tokens w*4 .. w*4+3
    for (int it = 0; it < 4; ++it) {
        const int tk = w * 4 + it;
        const float4 x = ((const float4*)(Lt + tk * N_EXP))[L];
        float sc[4];
        sc[0] = 1.0f / (1.0f + expf(-x.x));
        sc[1] = 1.0f / (1.0f + expf(-x.y));
        sc[2] = 1.0f / (1.0f + expf(-x.z));
        sc[3] = 1.0f / (1.0f + expf(-x.w));

        float v1 = -1.0f, v2 = -1.0f;
        int   i1 = 0,     i2 = 0;
        #pragma unroll
        for (int j = 0; j < 4; ++j) {
            const int idx = L * 4 + j;
            if (sc[j] > v1)      { v2 = v1; i2 = i1; v1 = sc[j]; i1 = idx; }
            else if (sc[j] > v2) { v2 = sc[j]; i2 = idx; }
        }
        // butterfly merge across each 16-lane group (= 64-expert group)
        #pragma unroll
        for (int offx = 1; offx < 16; offx <<= 1) {
            const float ov1 = __shfl_xor(v1, offx);
            const int   oi1 = __shfl_xor(i1, offx);
            const float ov2 = __shfl_xor(v2, offx);
            const int   oi2 = __shfl_xor(i2, offx);
            const bool o1_beats_m1 = (ov1 > v1) || (ov1 == v1 && oi1 < i1);
            if (o1_beats_m1) {
                const bool m1_beats_o2 = (v1 > ov2) || (v1 == ov2 && i1 < oi2);
                const float nv2 = m1_beats_o2 ? v1 : ov2;
                const int   ni2 = m1_beats_o2 ? i1 : oi2;
                v1 = ov1; i1 = oi1; v2 = nv2; i2 = ni2;
            } else {
                const bool o1_beats_m2 = (ov1 > v2) || (ov1 == v2 && oi1 < i2);
                v2 = o1_beats_m2 ? ov1 : v2;
                i2 = o1_beats_m2 ? oi1 : i2;
            }
        }
        float sum = 0.0f;
        #pragma unroll
        for (int g = 0; g < 4; ++g)
            sum += __shfl(v1, g * 16) + __shfl(v2, g * 16);
        const int   src = ((L >> 1) & 3) * 16;
        const float mv1 = __shfl(v1, src);
        const float mv2 = __shfl(v2, src);
        const int   mi1 = __shfl(i1, src);
        const int   mi2 = __shfl(i2, src);
        if (L < 8) {
            const float myv = (L & 1) ? mv2 : mv1;
            const int   myi = (L & 1) ? mi2 : mi1;
            out_idx[(size_t)(tok0 + tk) * 8 + L] = (float)myi;
            out_w  [(size_t)(tok0 + tk) * 8 + L] = myv * (2.5f / (sum + 1e-10f));
        }
    }
}

// ---------------- fallback (ws too small): fp32 VALU path ----------------
constexpr int FBM = 32;
constexpr int FBK = 16;
constexpr int FNC = D_MODEL / FBK;

__global__ __launch_bounds__(256) void gate_gemm_f32(
    const float* __restrict__ H, const float* __restrict__ W,
    float* __restrict__ logits)
{
    __shared__ float As[2][FBK][FBM + 4];
    __shared__ float Bs[2][FBK][N_EXP + 1];
    const int t = threadIdx.x, tx = t & 31, ty = t >> 5;
    const int tok0 = blockIdx.x * FBM, tokA = t >> 2, kqA = t & 3;
    float4 pa, pb[4];
    float acc[4][8];
    #pragma unroll
    for (int i = 0; i < 4; ++i)
        #pragma unroll
        for (int j = 0; j < 8; ++j) acc[i][j] = 0.0f;
    auto issue_loads = [&](int kc) {
        if (t < 128) pa = *(const float4*)(H + (size_t)(tok0 + tokA) * D_MODEL + kc + kqA * 4);
        #pragma unroll
        for (int j = 0; j < 4; ++j) {
            const int flat = t + 256 * j, e = flat >> 2, kq = flat & 3;
            pb[j] = *(const float4*)(W + (size_t)e * D_MODEL + kc + kq * 4);
        }
    };
    auto write_lds = [&](int buf) {
        if (t < 128) {
            As[buf][kqA * 4 + 0][tokA] = pa.x; As[buf][kqA * 4 + 1][tokA] = pa.y;
            As[buf][kqA * 4 + 2][tokA] = pa.z; As[buf][kqA * 4 + 3][tokA] = pa.w;
        }
        #pragma unroll
        for (int j = 0; j < 4; ++j) {
            const int flat = t + 256 * j, e = flat >> 2, kq = flat & 3;
            Bs[buf][kq * 4 + 0][e] = pb[j].x; Bs[buf][kq * 4 + 1][e] = pb[j].y;
            Bs[buf][kq * 4 + 2][e] = pb[j].z; Bs[buf][kq * 4 + 3][e] = pb[j].w;
        }
    };
    issue_loads(0); write_lds(0); __syncthreads();
    for (int c = 0; c < FNC; ++c) {
        const int buf = c & 1;
        if (c + 1 < FNC) issue_loads((c + 1) * FBK);
        #pragma unroll
        for (int k = 0; k < FBK; ++k) {
            const float4 av = *(const float4*)&As[buf][k][ty * 4];
            const float a[4] = {av.x, av.y, av.z, av.w};
            float b[8];
            #pragma unroll
            for (int j = 0; j < 8; ++j) b[j] = Bs[buf][k][tx + 32 * j];
            #pragma unroll
            for (int i = 0; i < 4; ++i)
                #pragma unroll
                for (int j = 0; j < 8; ++j) acc[i][j] = fmaf(a[i], b[j], acc[i][j]);
        }
        if (c + 1 < FNC) write_lds(buf ^ 1);
        __syncthreads();
    }
    #pragma unroll
    for (int i = 0; i < 4; ++i) {
        const size_t row = (size_t)(tok0 + ty * 4 + i) * N_EXP;
        #pragma unroll
        for (int j = 0; j < 8; ++j) logits[row + tx + 32 * j] = acc[i][j];
    }
}

__global__ __launch_bounds__(256) void topk_only(
    const float* __restrict__ logits,
    float* __restrict__ out_idx, float* __restrict__ out_w)
{
    const int token = blockIdx.x * 4 + (threadIdx.x >> 6);
    const int lane  = threadIdx.x & 63;
    const float4 x = *(const float4*)(logits + (size_t)token * N_EXP + lane * 4);
    float sc[4];
    sc[0] = 1.0f / (1.0f + expf(-x.x)); sc[1] = 1.0f / (1.0f + expf(-x.y));
    sc[2] = 1.0f / (1.0f + expf(-x.z)); sc[3] = 1.0f / (1.0f + expf(-x.w));
    float v1 = -1.0f, v2 = -1.0f; int i1 = 0, i2 = 0;
    #pragma unroll
    for (int j = 0; j < 4; ++j) {
        const int idx = lane * 4 + j;
        if (sc[j] > v1)      { v2 = v1; i2 = i1; v1 = sc[j]; i1 = idx; }
        else if (sc[j] > v2) { v2 = sc[j]; i2 = idx; }
    }
    #pragma unroll
    for (int offx = 1; offx < 16; offx <<= 1) {
        const float ov1 = __shfl_xor(v1, offx); const int oi1 = __shfl_xor(i1, offx);
        const float ov2 = __shfl_xor(v2, offx); const int oi2 = __shfl_xor(i2, offx);
        const bool o1_beats_m1 = (ov1 > v1) || (ov1 == v1 && oi1 < i1);
        if (o1_beats_m1) {
            const bool m1_beats_o2 = (v1 > ov2) || (v1 == ov2 && i1 < oi2);
            const float nv2 = m1_beats_o2 ? v1 : ov2;
            const int   ni2 = m1_beats_o2 ? i1 : oi2;
            v1 = ov1; i1 = oi1; v2 = nv2; i2 = ni2;
        } else {
            const bool o1_beats_m2 = (ov1 > v2) || (ov1 == v2 && oi1 < i2);
            v2 = o1_beats_m2 ? ov1 : v2; i2 = o1_beats_m2 ? oi1 : i2;
        }
    }
    float sum = 0.0f;
    #pragma unroll
    for (int g = 0; g < 4; ++g) sum += __shfl(v1, g * 16) + __shfl(v2, g * 16);
    const int src = ((lane >> 1) & 3) * 16;
    const float mv1 = __shfl(v1, src), mv2 = __shfl(v2, src);
    const int   mi1 = __shfl(i1, src), mi2 = __shfl(i2, src);
    if (lane < 8) {
        const float myv = (lane & 1) ? mv2 : mv1;
        const int   myi = (lane & 1) ? mi2 : mi1;
        out_idx[(size_t)token * 8 + lane] = (float)myi;
        out_w  [(size_t)token * 8 + lane] = myv * (2.5f / (sum + 1e-10f));
    }
}

extern "C" void kernel_launch(void* const* d_in, const int* in_sizes, int n_in,
                              void* d_out, int out_size, void* d_ws, size_t ws_size,
                              hipStream_t stream) {
    const float* H = (const float*)d_in[0];   // hidden_states [8192, 4096]
    const float* W = (const float*)d_in[1];   // gate_w        [256, 4096]

    float* out     = (float*)d_out;
    float* out_idx = out;                           // 8192*8
    float* out_w   = out + (size_t)N_TOKENS * 8;    // 8192*8
    float* logits  = out + (size_t)N_TOKENS * 16;   // 8192*256

    if (ws_size >= WS_NEED) {
        unsigned short* wsB = (unsigned short*)d_ws;
        static bool attr_done = []() {
            hipFuncSetAttribute((const void*)gate_fused,
                                hipFuncAttributeMaxDynamicSharedMemorySize,
                                (int)LDS_BYTES);
            return true;
        }();
        (void)attr_done;
        convert_w<<<dim3(NC * 4), dim3(256), 0, stream>>>(W, wsB);
        gate_fused<<<dim3(N_TOKENS / BM), dim3(512), LDS_BYTES, stream>>>(
            H, wsB, logits, out_idx, out_w);
    } else {
        gate_gemm_f32<<<dim3(N_TOKENS / FBM), dim3(256), 0, stream>>>(H, W, logits);
        topk_only<<<dim3(N_TOKENS / 4), dim3(256), 0, stream>>>(logits, out_idx, out_w);
    }
}

// Round 8
// 279.819 us; speedup vs baseline: 1.2602x; 1.0453x over previous
//
#include <hip/hip_runtime.h>
#include <math.h>

// Problem constants
constexpr int N_TOKENS = 8192;
constexpr int D_MODEL  = 4096;
constexpr int N_EXP    = 256;

// Fused one-shot GEMM: 32 tokens x 256 experts per block, no split-K.
constexpr int BM = 32;              // tokens per block
constexpr int BK = 32;              // K per chunk (= MFMA K)
constexpr int NC = D_MODEL / BK;    // 128 chunks

// ws B layout: [chunk c][plane hi/lo][256 exp x 32 k, XOR-swizzled granules]
constexpr int WPL = N_EXP * BK;     // 8192 ushorts per plane (16 KB)
constexpr int WCH = 2 * WPL;        // 16384 ushorts per chunk (32 KB)

// LDS layout (bytes):
//   [0, 16384)        A fp32, 4 stages x 4096 (DMA dest; linear per-thread slots)
//   [16384, 24576)    A bf16 hi/lo, 2 stages x 4096 (converted once per block)
//   [24576, 155648)   B bf16 hi/lo, 4 stages x 32768 (verbatim wsB chunk image)
constexpr int NB = 4;                   // B stages (prefetch depth 3)
constexpr int NA = 4;                   // A fp32 stages (prefetch distance 4)
constexpr int A_ST_U   = 2048;          // ushorts per fp32 A stage (4096 B)
constexpr int BB_USH   = 12288;         // ushort offset of B region (24576 B)
constexpr int B_ST_U   = WCH;           // 16384 ushorts per B stage
constexpr size_t LDS_BYTES = (size_t)(BB_USH + NB * B_ST_U) * sizeof(unsigned short); // 155648

// byte-offset constants for the opaque-asm LDS path
constexpr unsigned A32_ST_B   = 4096;     // fp32 A stage bytes
constexpr unsigned ABF_BASE_B = 16384;    // A bf16 region base
constexpr unsigned ABF_ST_B   = 4096;     // per stage (hi 2048 + lo 2048)
constexpr unsigned ABF_LO_B   = 2048;     // lo-plane offset within stage
constexpr unsigned B_BASE_B   = 24576;
constexpr unsigned B_ST_B     = 32768;
constexpr unsigned B_PLANE_B  = 16384;

constexpr size_t WS_NEED = (size_t)NC * WCH * sizeof(unsigned short);  // 4 MB

typedef __attribute__((ext_vector_type(8))) short short8;
typedef __attribute__((ext_vector_type(4))) float f32x4;
typedef __attribute__((ext_vector_type(2))) unsigned int u32x2;
typedef unsigned int u32;
typedef const __attribute__((address_space(1))) u32* gas_ptr;
typedef __attribute__((address_space(3))) u32* las_ptr;

static __device__ __forceinline__ unsigned short f2bf(float x) {
    union { float f; unsigned u; } v; v.f = x;
    unsigned r = v.u + 0x7fffu + ((v.u >> 16) & 1u);   // RNE
    return (unsigned short)(r >> 16);
}
static __device__ __forceinline__ float bf2f(unsigned short s) {
    union { unsigned u; float f; } v; v.u = ((unsigned)s) << 16;
    return v.f;
}

// Opaque LDS ops: raw byte-offset asm, invisible to the compiler's memory
// model, so it cannot insert its own vmcnt(0) drain for the global_load_lds
// DMAs — ordering is ours via counted vmcnt + lgkmcnt + sched_barrier.
static __device__ __forceinline__ short8 lds_read_s8(unsigned byte_off) {
    short8 r;
    asm volatile("ds_read_b128 %0, %1" : "=v"(r) : "v"(byte_off));
    return r;
}
static __device__ __forceinline__ f32x4 lds_read_f4(unsigned byte_off) {
    f32x4 r;
    asm volatile("ds_read_b128 %0, %1" : "=v"(r) : "v"(byte_off));
    return r;
}
static __device__ __forceinline__ void lds_write_b64(unsigned byte_off, u32 a, u32 b) {
    u32x2 v; v[0] = a; v[1] = b;
    asm volatile("ds_write_b64 %0, %1" :: "v"(byte_off), "v"(v));
}
// packed f32x2 -> bf16x2, RNE (dst.lo16 = bf16(lo), dst.hi16 = bf16(hi))
static __device__ __forceinline__ u32 cvtpk(float lo, float hi) {
    u32 r;
    asm volatile("v_cvt_pk_bf16_f32 %0, %1, %2" : "=v"(r) : "v"(lo), "v"(hi));
    return r;
}

// ---- W fp32 -> bf16 hi/lo, chunk-major + XOR-swizzled for global_load_lds ----
__global__ __launch_bounds__(256) void convert_w(
    const float* __restrict__ W, unsigned short* __restrict__ wsB)
{
    const int c    = blockIdx.x >> 2;           // chunk
    const int q    = blockIdx.x & 3;            // expert quarter
    const int t    = threadIdx.x;
    const int e    = q * 64 + (t >> 2);
    const int slot = t & 3;                     // physical 16B granule in row
    const int kq   = slot ^ ((e >> 1) & 3);     // logical k-granule (8 ushorts)

    const float* src = W + (size_t)e * D_MODEL + c * BK + kq * 8;
    const float4 x0 = *(const float4*)src;
    const float4 x1 = *(const float4*)(src + 4);
    const float xs[8] = {x0.x, x0.y, x0.z, x0.w, x1.x, x1.y, x1.z, x1.w};
    short8 vh, vl;
    #pragma unroll
    for (int j = 0; j < 8; ++j) {
        const unsigned short h = f2bf(xs[j]);
        vh[j] = (short)h;
        vl[j] = (short)f2bf(xs[j] - bf2f(h));
    }
    unsigned short* dst = wsB + (size_t)c * WCH + e * 32 + slot * 8;
    *(short8*)dst         = vh;
    *(short8*)(dst + WPL) = vl;
}

// ---- fused GEMM (bf16x3) + sigmoid + group-top2 + coalesced logits ----
// 8 waves x 32 experts. A is converted fp32->bf16x2 ONCE per block per chunk
// (threads 0-255, wave-private fp32 readback, cvt_pk, ds_write to a shared
// double-buffered bf16 tile) instead of 8x-redundant in-register split.
// Counted waits vmcnt(15)/vmcnt(12) keep 3 iterations of loads in flight.
__global__ __launch_bounds__(512, 1) void gate_fused(
    const float* __restrict__ H, const unsigned short* __restrict__ wsB,
    float* __restrict__ logits, float* __restrict__ out_idx, float* __restrict__ out_w)
{
    extern __shared__ unsigned short lds[];

    const int t      = threadIdx.x;
    const int L      = t & 63;
    const int w      = t >> 6;          // wave 0..7: experts [w*32, w*32+32)
    const int lane16 = L & 15;
    const int g4     = L >> 4;          // k-granule for frag reads
    const int tok0   = blockIdx.x * BM;
    const int phase  = (blockIdx.x & 7) << 4;   // per-XCD chunk rotation

    // A staging (threads 0..255): thread t owns row rA=t>>3, 4-float granule
    // qA=t&7 (k = qA*4..+3). fp32 slot is LINEAR (byte t*16, own-wave DMA dest
    // = own-thread readback; no swizzle needed). bf16 dest applies the granule
    // XOR so frag reads are 2-way-bank-clean.
    const int rA = t >> 3;
    const int qA = t & 7;
    const float* srcA = H + (size_t)(tok0 + (rA & 31)) * D_MODEL + qA * 4;
    const unsigned myf32 = (unsigned)((t & 255) * 16);
    const unsigned mybf  = (unsigned)((rA & 31) * 64 +
                            ((((qA >> 1) ^ ((rA >> 1) & 3))) << 4) + (qA & 1) * 8);

    // loop-invariant fragment byte offsets
    unsigned offA[2], offB[2];
    #pragma unroll
    for (int mi = 0; mi < 2; ++mi) {
        const int row = mi * 16 + lane16;
        offA[mi] = (unsigned)(row * 64 + ((g4 ^ ((row >> 1) & 3)) << 4));
    }
    #pragma unroll
    for (int ni = 0; ni < 2; ++ni) {
        const int e = w * 32 + ni * 16 + lane16;
        offB[ni] = (unsigned)((e * 32 + ((g4 ^ ((e >> 1) & 3)) << 3)) * 2);
    }

    f32x4 acc[2][2];
    #pragma unroll
    for (int mi = 0; mi < 2; ++mi)
        #pragma unroll
        for (int ni = 0; ni < 2; ++ni) acc[mi][ni] = (f32x4)0.0f;

    auto dmaB = [&](int pc, int s) {
        const unsigned short* src = wsB + (size_t)pc * WCH;
        unsigned short* dst = lds + BB_USH + s * B_ST_U;
        #pragma unroll
        for (int p = 0; p < 2; ++p)
            #pragma unroll
            for (int i = 0; i < 2; ++i) {
                const int o = p * WPL + (w * 2 + i) * 512;   // ushort offset
                __builtin_amdgcn_global_load_lds(
                    (gas_ptr)(const void*)(src + o + L * 8),
                    (las_ptr)(void*)(dst + o), 16, 0, 0);
            }
    };

    auto dmaA = [&](int pc, int s) {       // only called for t < 256
        __builtin_amdgcn_global_load_lds(
            (gas_ptr)(const void*)(srcA + (size_t)pc * BK),
            (las_ptr)(void*)(lds + s * A_ST_U + w * 512), 16, 0, 0);
    };

    // convert A(chunk in fp32 stage s32) -> bf16 stage sbf (threads 0-255)
    auto convertA = [&](int s32, int sbf) {
        f32x4 xa = lds_read_f4((unsigned)s32 * A32_ST_B + myf32);
        asm volatile("s_waitcnt lgkmcnt(0)" ::: "memory");
        __builtin_amdgcn_sched_barrier(0);
        const u32 h01 = cvtpk(xa[0], xa[1]);
        const u32 h23 = cvtpk(xa[2], xa[3]);
        const float r0 = xa[0] - __uint_as_float(h01 << 16);
        const float r1 = xa[1] - __uint_as_float(h01 & 0xffff0000u);
        const float r2 = xa[2] - __uint_as_float(h23 << 16);
        const float r3 = xa[3] - __uint_as_float(h23 & 0xffff0000u);
        const u32 l01 = cvtpk(r0, r1);
        const u32 l23 = cvtpk(r2, r3);
        const unsigned dst = ABF_BASE_B + (unsigned)sbf * ABF_ST_B + mybf;
        lds_write_b64(dst, h01, h23);
        lds_write_b64(dst + ABF_LO_B, l01, l23);
    };

    auto pch = [&](int c) { return (c + phase) & (NC - 1); };

    // Prologue: g(-3)=[B(0),A(0),A(1)] (6/4 ops), g(-2)=[B(1),A(2)] (5/4),
    // g(-1)=[B(2),A(3)] (5/4). Drain g(-3): vmcnt(10)/vmcnt(8); convert A(0);
    // barrier publishes bf16 A(0).
    dmaB(pch(0), 0);
    if (t < 256) { dmaA(pch(0), 0); dmaA(pch(1), 1); }
    __builtin_amdgcn_sched_barrier(0);
    dmaB(pch(1), 1);
    if (t < 256) dmaA(pch(2), 2);
    __builtin_amdgcn_sched_barrier(0);
    dmaB(pch(2), 2);
    if (t < 256) dmaA(pch(3), 3);
    __builtin_amdgcn_sched_barrier(0);
    if (t < 256) { asm volatile("s_waitcnt vmcnt(10)" ::: "memory"); }
    else         { asm volatile("s_waitcnt vmcnt(8)"  ::: "memory"); }
    __builtin_amdgcn_sched_barrier(0);
    if (t < 256) convertA(0, 0);
    asm volatile("s_waitcnt lgkmcnt(0)" ::: "memory");
    __builtin_amdgcn_s_barrier();

    // Steady: iter c issues g(c)=[B(c+3)->stage (c+3)&3, A(c+4)->stage c&3];
    // vmcnt(15)/(12) drains g(c-3) = {B(c) (read now), A(c+1) (converted now,
    // published by this iter's barrier, frag-read next iter)}. Tail iters
    // issue clamped redundant loads so each group keeps its exact op count.
    for (int c = 0; c < NC; ++c) {
        const int cB = (c + 3 < NC) ? c + 3 : NC - 1;
        const int cA = (c + 4 < NC) ? c + 4 : NC - 1;
        dmaB(pch(cB), (c + 3) & 3);
        if (t < 256) dmaA(pch(cA), c & 3);
        __builtin_amdgcn_sched_barrier(0);
        if (t < 256) { asm volatile("s_waitcnt vmcnt(15)" ::: "memory"); }
        else         { asm volatile("s_waitcnt vmcnt(12)" ::: "memory"); }
        __builtin_amdgcn_sched_barrier(0);

        // fragment reads: bf16 A stage (c&1), B stage (c&3)
        const unsigned aB = ABF_BASE_B + (unsigned)(c & 1) * ABF_ST_B;
        const unsigned bB = B_BASE_B + (unsigned)(c & 3) * B_ST_B;
        const short8 ah0 = lds_read_s8(aB + offA[0]);
        const short8 ah1 = lds_read_s8(aB + offA[1]);
        const short8 al0 = lds_read_s8(aB + ABF_LO_B + offA[0]);
        const short8 al1 = lds_read_s8(aB + ABF_LO_B + offA[1]);
        const short8 bh0 = lds_read_s8(bB + offB[0]);
        const short8 bl0 = lds_read_s8(bB + B_PLANE_B + offB[0]);
        const short8 bh1 = lds_read_s8(bB + offB[1]);
        const short8 bl1 = lds_read_s8(bB + B_PLANE_B + offB[1]);
        asm volatile("s_waitcnt lgkmcnt(0)" ::: "memory");
        __builtin_amdgcn_sched_barrier(0);   // rule #18: nothing hoists above

        // convert NEXT chunk's A while MFMAs run (publishes at this barrier)
        if (t < 256 && c + 1 < NC) convertA((c + 1) & 3, (c + 1) & 1);

        __builtin_amdgcn_s_setprio(1);
        acc[0][0] = __builtin_amdgcn_mfma_f32_16x16x32_bf16(ah0, bh0, acc[0][0], 0, 0, 0);
        acc[0][0] = __builtin_amdgcn_mfma_f32_16x16x32_bf16(ah0, bl0, acc[0][0], 0, 0, 0);
        acc[0][0] = __builtin_amdgcn_mfma_f32_16x16x32_bf16(al0, bh0, acc[0][0], 0, 0, 0);
        acc[1][0] = __builtin_amdgcn_mfma_f32_16x16x32_bf16(ah1, bh0, acc[1][0], 0, 0, 0);
        acc[1][0] = __builtin_amdgcn_mfma_f32_16x16x32_bf16(ah1, bl0, acc[1][0], 0, 0, 0);
        acc[1][0] = __builtin_amdgcn_mfma_f32_16x16x32_bf16(al1, bh0, acc[1][0], 0, 0, 0);
        acc[0][1] = __builtin_amdgcn_mfma_f32_16x16x32_bf16(ah0, bh1, acc[0][1], 0, 0, 0);
        acc[0][1] = __builtin_amdgcn_mfma_f32_16x16x32_bf16(ah0, bl1, acc[0][1], 0, 0, 0);
        acc[0][1] = __builtin_amdgcn_mfma_f32_16x16x32_bf16(al0, bh1, acc[0][1], 0, 0, 0);
        acc[1][1] = __builtin_amdgcn_mfma_f32_16x16x32_bf16(ah1, bh1, acc[1][1], 0, 0, 0);
        acc[1][1] = __builtin_amdgcn_mfma_f32_16x16x32_bf16(ah1, bl1, acc[1][1], 0, 0, 0);
        acc[1][1] = __builtin_amdgcn_mfma_f32_16x16x32_bf16(al1, bh1, acc[1][1], 0, 0, 0);
        __builtin_amdgcn_s_setprio(0);

        asm volatile("s_waitcnt lgkmcnt(0)" ::: "memory");
        __builtin_amdgcn_s_barrier();
    }
    // Deterministic full drain (clamped tail DMAs) before LDS re-aliasing.
    asm volatile("s_waitcnt vmcnt(0) lgkmcnt(0)" ::: "memory");
    __builtin_amdgcn_sched_barrier(0);
    __builtin_amdgcn_s_barrier();

    // ---- epilogue: LDS-transpose bounce, coalesced logits, fused topk ----
    float* Lt = (float*)lds;            // [32][256] fp32 = 32 KB (aliases stages)
    #pragma unroll
    for (int mi = 0; mi < 2; ++mi)
        #pragma unroll
        for (int ni = 0; ni < 2; ++ni)
            #pragma unroll
            for (int r = 0; r < 4; ++r) {
                const int tok = mi * 16 + g4 * 4 + r;       // C/D: row = quad*4+reg
                const int col = w * 32 + ni * 16 + lane16;  // C/D: col = lane&15
                Lt[tok * N_EXP + col] = acc[mi][ni][r];
            }
    __syncthreads();

    // coalesced logits store: 8192 floats = 2048 float4, 4 per thread
    float4*       Lg  = (float4*)(logits + (size_t)tok0 * N_EXP);
    const float4* Lt4 = (const float4*)Lt;
    #pragma unroll
    for (int i = 0; i < 4; ++i) Lg[i * 512 + t] = Lt4[i * 512 + t];

    // topk: wave w handles local tokens w*4 .. w*4+3
    for (int it = 0; it < 4; ++it) {
        const int tk = w * 4 + it;
        const float4 x = ((const float4*)(Lt + tk * N_EXP))[L];
        float sc[4];
        sc[0] = 1.0f / (1.0f + expf(-x.x));
        sc[1] = 1.0f / (1.0f + expf(-x.y));
        sc[2] = 1.0f / (1.0f + expf(-x.z));
        sc[3] = 1.0f / (1.0f + expf(-x.w));

        float v1 = -1.0f, v2 = -1.0f;
        int   i1 = 0,     i2 = 0;
        #pragma unroll
        for (int j = 0; j < 4; ++j) {
            const int idx = L * 4 + j;
            if (sc[j] > v1)      { v2 = v1; i2 = i1; v1 = sc[j]; i1 = idx; }
            else if (sc[j] > v2) { v2 = sc[j]; i2 = idx; }
        }
        // butterfly merge across each 16-lane group (= 64-expert group)
        #pragma unroll
        for (int offx = 1; offx < 16; offx <<= 1) {
            const float ov1 = __shfl_xor(v1, offx);
            const int   oi1 = __shfl_xor(i1, offx);
            const float ov2 = __shfl_xor(v2, offx);
            const int   oi2 = __shfl_xor(i2, offx);
            const bool o1_beats_m1 = (ov1 > v1) || (ov1 == v1 && oi1 < i1);
            if (o1_beats_m1) {
                const bool m1_beats_o2 = (v1 > ov2) || (v1 == ov2 && i1 < oi2);
                const float nv2 = m1_beats_o2 ? v1 : ov2;
                const int   ni2 = m1_beats_o2 ? i1 : oi2;
                v1 = ov1; i1 = oi1; v2 = nv2; i2 = ni2;
            } else {
                const bool o1_beats_m2 = (ov1 > v2) || (ov1 == v2 && oi1 < i2);
                v2 = o1_beats_m2 ? ov1 : v2;
                i2 = o1_beats_m2 ? oi1 : i2;
            }
        }
        float sum = 0.0f;
        #pragma unroll
        for (int g = 0; g < 4; ++g)
            sum += __shfl(v1, g * 16) + __shfl(v2, g * 16);
        const int   src = ((L >> 1) & 3) * 16;
        const float mv1 = __shfl(v1, src);
        const float mv2 = __shfl(v2, src);
        const int   mi1 = __shfl(i1, src);
        const int   mi2 = __shfl(i2, src);
        if (L < 8) {
            const float myv = (L & 1) ? mv2 : mv1;
            const int   myi = (L & 1) ? mi2 : mi1;
            out_idx[(size_t)(tok0 + tk) * 8 + L] = (float)myi;
            out_w  [(size_t)(tok0 + tk) * 8 + L] = myv * (2.5f / (sum + 1e-10f));
        }
    }
}

// ---------------- fallback (ws too small): fp32 VALU path ----------------
constexpr int FBM = 32;
constexpr int FBK = 16;
constexpr int FNC = D_MODEL / FBK;

__global__ __launch_bounds__(256) void gate_gemm_f32(
    const float* __restrict__ H, const float* __restrict__ W,
    float* __restrict__ logits)
{
    __shared__ float As[2][FBK][FBM + 4];
    __shared__ float Bs[2][FBK][N_EXP + 1];
    const int t = threadIdx.x, tx = t & 31, ty = t >> 5;
    const int tok0 = blockIdx.x * FBM, tokA = t >> 2, kqA = t & 3;
    float4 pa, pb[4];
    float acc[4][8];
    #pragma unroll
    for (int i = 0; i < 4; ++i)
        #pragma unroll
        for (int j = 0; j < 8; ++j) acc[i][j] = 0.0f;
    auto issue_loads = [&](int kc) {
        if (t < 128) pa = *(const float4*)(H + (size_t)(tok0 + tokA) * D_MODEL + kc + kqA * 4);
        #pragma unroll
        for (int j = 0; j < 4; ++j) {
            const int flat = t + 256 * j, e = flat >> 2, kq = flat & 3;
            pb[j] = *(const float4*)(W + (size_t)e * D_MODEL + kc + kq * 4);
        }
    };
    auto write_lds = [&](int buf) {
        if (t < 128) {
            As[buf][kqA * 4 + 0][tokA] = pa.x; As[buf][kqA * 4 + 1][tokA] = pa.y;
            As[buf][kqA * 4 + 2][tokA] = pa.z; As[buf][kqA * 4 + 3][tokA] = pa.w;
        }
        #pragma unroll
        for (int j = 0; j < 4; ++j) {
            const int flat = t + 256 * j, e = flat >> 2, kq = flat & 3;
            Bs[buf][kq * 4 + 0][e] = pb[j].x; Bs[buf][kq * 4 + 1][e] = pb[j].y;
            Bs[buf][kq * 4 + 2][e] = pb[j].z; Bs[buf][kq * 4 + 3][e] = pb[j].w;
        }
    };
    issue_loads(0); write_lds(0); __syncthreads();
    for (int c = 0; c < FNC; ++c) {
        const int buf = c & 1;
        if (c + 1 < FNC) issue_loads((c + 1) * FBK);
        #pragma unroll
        for (int k = 0; k < FBK; ++k) {
            const float4 av = *(const float4*)&As[buf][k][ty * 4];
            const float a[4] = {av.x, av.y, av.z, av.w};
            float b[8];
            #pragma unroll
            for (int j = 0; j < 8; ++j) b[j] = Bs[buf][k][tx + 32 * j];
            #pragma unroll
            for (int i = 0; i < 4; ++i)
                #pragma unroll
                for (int j = 0; j < 8; ++j) acc[i][j] = fmaf(a[i], b[j], acc[i][j]);
        }
        if (c + 1 < FNC) write_lds(buf ^ 1);
        __syncthreads();
    }
    #pragma unroll
    for (int i = 0; i < 4; ++i) {
        const size_t row = (size_t)(tok0 + ty * 4 + i) * N_EXP;
        #pragma unroll
        for (int j = 0; j < 8; ++j) logits[row + tx + 32 * j] = acc[i][j];
    }
}

__global__ __launch_bounds__(256) void topk_only(
    const float* __restrict__ logits,
    float* __restrict__ out_idx, float* __restrict__ out_w)
{
    const int token = blockIdx.x * 4 + (threadIdx.x >> 6);
    const int lane  = threadIdx.x & 63;
    const float4 x = *(const float4*)(logits + (size_t)token * N_EXP + lane * 4);
    float sc[4];
    sc[0] = 1.0f / (1.0f + expf(-x.x)); sc[1] = 1.0f / (1.0f + expf(-x.y));
    sc[2] = 1.0f / (1.0f + expf(-x.z)); sc[3] = 1.0f / (1.0f + expf(-x.w));
    float v1 = -1.0f, v2 = -1.0f; int i1 = 0, i2 = 0;
    #pragma unroll
    for (int j = 0; j < 4; ++j) {
        const int idx = lane * 4 + j;
        if (sc[j] > v1)      { v2 = v1; i2 = i1; v1 = sc[j]; i1 = idx; }
        else if (sc[j] > v2) { v2 = sc[j]; i2 = idx; }
    }
    #pragma unroll
    for (int offx = 1; offx < 16; offx <<= 1) {
        const float ov1 = __shfl_xor(v1, offx); const int oi1 = __shfl_xor(i1, offx);
        const float ov2 = __shfl_xor(v2, offx); const int oi2 = __shfl_xor(i2, offx);
        const bool o1_beats_m1 = (ov1 > v1) || (ov1 == v1 && oi1 < i1);
        if (o1_beats_m1) {
            const bool m1_beats_o2 = (v1 > ov2) || (v1 == ov2 && i1 < oi2);
            const float nv2 = m1_beats_o2 ? v1 : ov2;
            const int   ni2 = m1_beats_o2 ? i1 : oi2;
            v1 = ov1; i1 = oi1; v2 = nv2; i2 = ni2;
        } else {
            const bool o1_beats_m2 = (ov1 > v2) || (ov1 == v2 && oi1 < i2);
            v2 = o1_beats_m2 ? ov1 : v2; i2 = o1_beats_m2 ? oi1 : i2;
        }
    }
    float sum = 0.0f;
    #pragma unroll
    for (int g = 0; g < 4; ++g) sum += __shfl(v1, g * 16) + __shfl(v2, g * 16);
    const int src = ((lane >> 1) & 3) * 16;
    const float mv1 = __shfl(v1, src), mv2 = __shfl(v2, src);
    const int   mi1 = __shfl(i1, src), mi2 = __shfl(i2, src);
    if (lane < 8) {
        const float myv = (lane & 1) ? mv2 : mv1;
        const int   myi = (lane & 1) ? mi2 : mi1;
        out_idx[(size_t)token * 8 + lane] = (float)myi;
        out_w  [(size_t)token * 8 + lane] = myv * (2.5f / (sum + 1e-10f));
    }
}

extern "C" void kernel_launch(void* const* d_in, const int* in_sizes, int n_in,
                              void* d_out, int out_size, void* d_ws, size_t ws_size,
                              hipStream_t stream) {
    const float* H = (const float*)d_in[0];   // hidden_states [8192, 4096]
    const float* W = (const float*)d_in[1];   // gate_w        [256, 4096]

    float* out     = (float*)d_out;
    float* out_idx = out;                           // 8192*8
    float* out_w   = out + (size_t)N_TOKENS * 8;    // 8192*8
    float* logits  = out + (size_t)N_TOKENS * 16;   // 8192*256

    if (ws_size >= WS_NEED) {
        unsigned short* wsB = (unsigned short*)d_ws;
        static bool attr_done = []() {
            hipFuncSetAttribute((const void*)gate_fused,
                                hipFuncAttributeMaxDynamicSharedMemorySize,
                                (int)LDS_BYTES);
            return true;
        }();
        (void)attr_done;
        convert_w<<<dim3(NC * 4), dim3(256), 0, stream>>>(W, wsB);
        gate_fused<<<dim3(N_TOKENS / BM), dim3(512), LDS_BYTES, stream>>>(
            H, wsB, logits, out_idx, out_w);
    } else {
        gate_gemm_f32<<<dim3(N_TOKENS / FBM), dim3(256), 0, stream>>>(H, W, logits);
        topk_only<<<dim3(N_TOKENS / 4), dim3(256), 0, stream>>>(logits, out_idx, out_w);
    }
}

// Round 9
// 275.561 us; speedup vs baseline: 1.2797x; 1.0155x over previous
//
#include <hip/hip_runtime.h>
#include <math.h>

// Problem constants
constexpr int N_TOKENS = 8192;
constexpr int D_MODEL  = 4096;
constexpr int N_EXP    = 256;

// Fused one-shot GEMM: 32 tokens x 256 experts per block, no split-K.
// 2 chunks per barrier window (64 windows of K=64).
constexpr int BM = 32;              // tokens per block
constexpr int BK = 32;              // K per chunk (= MFMA K)
constexpr int NC = D_MODEL / BK;    // 128 chunks
constexpr int NW = NC / 2;          // 64 windows

// ws B layout: [chunk c][plane hi/lo][256 exp x 32 k, XOR-swizzled granules]
constexpr int WPL = N_EXP * BK;     // 8192 ushorts per plane (16 KB)
constexpr int WCH = 2 * WPL;        // 16384 ushorts per chunk (32 KB)

// LDS layout (bytes):
//   [0, 16384)        A fp32, 4 stages x 4096 (DMA dest; linear per-thread slots)
//   [16384, 32768)    A bf16 hi/lo, 4 stages x 4096 (converted once per block)
//   [32768, 163840)   B bf16 hi/lo, 4 stages x 32768 (verbatim wsB chunk image)
constexpr int A_ST_U   = 2048;          // ushorts per fp32 A stage (4096 B)
constexpr int BB_USH   = 16384;         // ushort offset of B region (32768 B)
constexpr int B_ST_U   = WCH;           // 16384 ushorts per B stage
constexpr size_t LDS_BYTES = (size_t)(BB_USH + 4 * B_ST_U) * sizeof(unsigned short); // 163840 (160 KB)

// byte-offset constants for the opaque-asm LDS path
constexpr unsigned A32_ST_B   = 4096;     // fp32 A stage bytes
constexpr unsigned ABF_BASE_B = 16384;    // A bf16 region base
constexpr unsigned ABF_ST_B   = 4096;     // per stage (hi 2048 + lo 2048)
constexpr unsigned ABF_LO_B   = 2048;     // lo-plane offset within stage
constexpr unsigned B_BASE_B   = 32768;
constexpr unsigned B_ST_B     = 32768;
constexpr unsigned B_PLANE_B  = 16384;

constexpr size_t WS_NEED = (size_t)NC * WCH * sizeof(unsigned short);  // 4 MB

typedef __attribute__((ext_vector_type(8))) short short8;
typedef __attribute__((ext_vector_type(4))) float f32x4;
typedef __attribute__((ext_vector_type(2))) unsigned int u32x2;
typedef unsigned int u32;
typedef const __attribute__((address_space(1))) u32* gas_ptr;
typedef __attribute__((address_space(3))) u32* las_ptr;

static __device__ __forceinline__ unsigned short f2bf(float x) {
    union { float f; unsigned u; } v; v.f = x;
    unsigned r = v.u + 0x7fffu + ((v.u >> 16) & 1u);   // RNE
    return (unsigned short)(r >> 16);
}
static __device__ __forceinline__ float bf2f(unsigned short s) {
    union { unsigned u; float f; } v; v.u = ((unsigned)s) << 16;
    return v.f;
}

// Opaque LDS ops: raw byte-offset asm, invisible to the compiler's memory
// model, so it cannot insert its own vmcnt(0) drain for the global_load_lds
// DMAs — ordering is ours via counted vmcnt + lgkmcnt + sched_barrier.
static __device__ __forceinline__ short8 lds_read_s8(unsigned byte_off) {
    short8 r;
    asm volatile("ds_read_b128 %0, %1" : "=v"(r) : "v"(byte_off));
    return r;
}
static __device__ __forceinline__ f32x4 lds_read_f4(unsigned byte_off) {
    f32x4 r;
    asm volatile("ds_read_b128 %0, %1" : "=v"(r) : "v"(byte_off));
    return r;
}
static __device__ __forceinline__ void lds_write_b64(unsigned byte_off, u32 a, u32 b) {
    u32x2 v; v[0] = a; v[1] = b;
    asm volatile("ds_write_b64 %0, %1" :: "v"(byte_off), "v"(v));
}
// packed f32x2 -> bf16x2, RNE (dst.lo16 = bf16(lo), dst.hi16 = bf16(hi))
static __device__ __forceinline__ u32 cvtpk(float lo, float hi) {
    u32 r;
    asm volatile("v_cvt_pk_bf16_f32 %0, %1, %2" : "=v"(r) : "v"(lo), "v"(hi));
    return r;
}

// ---- W fp32 -> bf16 hi/lo, chunk-major + XOR-swizzled for global_load_lds ----
__global__ __launch_bounds__(256) void convert_w(
    const float* __restrict__ W, unsigned short* __restrict__ wsB)
{
    const int c    = blockIdx.x >> 2;           // chunk
    const int q    = blockIdx.x & 3;            // expert quarter
    const int t    = threadIdx.x;
    const int e    = q * 64 + (t >> 2);
    const int slot = t & 3;                     // physical 16B granule in row
    const int kq   = slot ^ ((e >> 1) & 3);     // logical k-granule (8 ushorts)

    const float* src = W + (size_t)e * D_MODEL + c * BK + kq * 8;
    const float4 x0 = *(const float4*)src;
    const float4 x1 = *(const float4*)(src + 4);
    const float xs[8] = {x0.x, x0.y, x0.z, x0.w, x1.x, x1.y, x1.z, x1.w};
    short8 vh, vl;
    #pragma unroll
    for (int j = 0; j < 8; ++j) {
        const unsigned short h = f2bf(xs[j]);
        vh[j] = (short)h;
        vl[j] = (short)f2bf(xs[j] - bf2f(h));
    }
    unsigned short* dst = wsB + (size_t)c * WCH + e * 32 + slot * 8;
    *(short8*)dst         = vh;
    *(short8*)(dst + WPL) = vl;
}

// ---- fused GEMM (bf16x3) + sigmoid + group-top2 + coalesced logits ----
// 8 waves x 32 experts; 2 chunks per barrier window (64 barriers, 24 MFMA +
// one shared lgkmcnt(0) per window). A converted once per block per chunk;
// the convert's fp32 read is issued WITH the fragment reads (no serial
// second wait). Counted vmcnt(10)/(8) keeps one full window of loads in
// flight across barriers.
__global__ __launch_bounds__(512, 1) void gate_fused(
    const float* __restrict__ H, const unsigned short* __restrict__ wsB,
    float* __restrict__ logits, float* __restrict__ out_idx, float* __restrict__ out_w)
{
    extern __shared__ unsigned short lds[];

    const int t      = threadIdx.x;
    const int L      = t & 63;
    const int w      = t >> 6;          // wave 0..7: experts [w*32, w*32+32)
    const int lane16 = L & 15;
    const int g4     = L >> 4;          // k-granule for frag reads
    const int tok0   = blockIdx.x * BM;
    const int phase  = (blockIdx.x & 7) << 4;   // per-XCD chunk rotation (even)

    // A staging (threads 0..255): thread t owns row rA=t>>3, 4-float granule
    // qA=t&7. fp32 slot LINEAR (byte (t&255)*16; own-wave DMA = own-thread
    // readback). bf16 dest applies the granule XOR for bank-clean frag reads.
    const int rA = t >> 3;
    const int qA = t & 7;
    const float* srcA = H + (size_t)(tok0 + (rA & 31)) * D_MODEL + qA * 4;
    const unsigned myf32 = (unsigned)((t & 255) * 16);
    const unsigned mybf  = (unsigned)((rA & 31) * 64 +
                            ((((qA >> 1) ^ ((rA >> 1) & 3))) << 4) + (qA & 1) * 8);

    // loop-invariant fragment byte offsets
    unsigned offA[2], offB[2];
    #pragma unroll
    for (int mi = 0; mi < 2; ++mi) {
        const int row = mi * 16 + lane16;
        offA[mi] = (unsigned)(row * 64 + ((g4 ^ ((row >> 1) & 3)) << 4));
    }
    #pragma unroll
    for (int ni = 0; ni < 2; ++ni) {
        const int e = w * 32 + ni * 16 + lane16;
        offB[ni] = (unsigned)((e * 32 + ((g4 ^ ((e >> 1) & 3)) << 3)) * 2);
    }

    f32x4 acc[2][2];
    #pragma unroll
    for (int mi = 0; mi < 2; ++mi)
        #pragma unroll
        for (int ni = 0; ni < 2; ++ni) acc[mi][ni] = (f32x4)0.0f;

    auto dmaB = [&](int pc, int s) {
        const unsigned short* src = wsB + (size_t)pc * WCH;
        unsigned short* dst = lds + BB_USH + s * B_ST_U;
        #pragma unroll
        for (int p = 0; p < 2; ++p)
            #pragma unroll
            for (int i = 0; i < 2; ++i) {
                const int o = p * WPL + (w * 2 + i) * 512;   // ushort offset
                __builtin_amdgcn_global_load_lds(
                    (gas_ptr)(const void*)(src + o + L * 8),
                    (las_ptr)(void*)(dst + o), 16, 0, 0);
            }
    };

    auto dmaA = [&](int pc, int s) {       // only called for t < 256
        __builtin_amdgcn_global_load_lds(
            (gas_ptr)(const void*)(srcA + (size_t)pc * BK),
            (las_ptr)(void*)(lds + s * A_ST_U + w * 512), 16, 0, 0);
    };

    // cvt fp32x4 (already in regs) -> bf16 hi/lo, write to bf16 stage (c&3)
    auto cvtWriteA = [&](const f32x4& xa, int c) {
        const u32 h01 = cvtpk(xa[0], xa[1]);
        const u32 h23 = cvtpk(xa[2], xa[3]);
        const float r0 = xa[0] - __uint_as_float(h01 << 16);
        const float r1 = xa[1] - __uint_as_float(h01 & 0xffff0000u);
        const float r2 = xa[2] - __uint_as_float(h23 << 16);
        const float r3 = xa[3] - __uint_as_float(h23 & 0xffff0000u);
        const u32 l01 = cvtpk(r0, r1);
        const u32 l23 = cvtpk(r2, r3);
        const unsigned dst = ABF_BASE_B + (unsigned)(c & 3) * ABF_ST_B + mybf;
        lds_write_b64(dst, h01, h23);
        lds_write_b64(dst + ABF_LO_B, l01, l23);
    };

    auto pch = [&](int c) { return (c + phase) & (NC - 1); };

    // Prologue. pre-group {A(0),A(1)} (2 ops, t<256); g(-1) = {B(0)x4,B(1)x4,
    // A(2),A(3)} (10/8 ops). vmcnt(10)/(8) drains the pre-group; convert
    // chunks 0,1; barrier publishes bf16 A(0),A(1).
    if (t < 256) { dmaA(pch(0), 0); dmaA(pch(1), 1); }
    __builtin_amdgcn_sched_barrier(0);
    dmaB(pch(0), 0);
    dmaB(pch(1), 1);
    if (t < 256) { dmaA(pch(2), 2); dmaA(pch(3), 3); }
    __builtin_amdgcn_sched_barrier(0);
    if (t < 256) { asm volatile("s_waitcnt vmcnt(10)" ::: "memory"); }
    else         { asm volatile("s_waitcnt vmcnt(8)"  ::: "memory"); }
    __builtin_amdgcn_sched_barrier(0);
    if (t < 256) {
        f32x4 p0 = lds_read_f4(0u * A32_ST_B + myf32);
        f32x4 p1 = lds_read_f4(1u * A32_ST_B + myf32);
        asm volatile("s_waitcnt lgkmcnt(0)" ::: "memory");
        __builtin_amdgcn_sched_barrier(0);
        cvtWriteA(p0, 0);
        cvtWriteA(p1, 1);
    }
    asm volatile("s_waitcnt lgkmcnt(0)" ::: "memory");
    __builtin_amdgcn_s_barrier();

    // Steady: window W computes chunks c0=2W, c1=2W+1. g(W) issues
    // {B(2W+2),B(2W+3) -> stages (2W+2)&3,(2W+3)&3; A(2W+4),A(2W+5) -> fp32
    // stages (2W+4)&3,(2W+5)&3}. vmcnt(10)/(8) drains g(W-1) = {B(c0),B(c1)
    // (read now), A(c0+2),A(c1+2) (converted now, published by this window's
    // barrier)}. Tail windows issue clamped redundant loads (op count exact);
    // clamped stores land in stages never read again.
    for (int W = 0; W < NW; ++W) {
        const int c0 = 2 * W, c1 = c0 + 1;
        const int cB0 = (c0 + 2 < NC) ? c0 + 2 : NC - 1;
        const int cB1 = (c1 + 2 < NC) ? c1 + 2 : NC - 1;
        const int cA0 = (c0 + 4 < NC) ? c0 + 4 : NC - 1;
        const int cA1 = (c1 + 4 < NC) ? c1 + 4 : NC - 1;
        dmaB(pch(cB0), (c0 + 2) & 3);
        dmaB(pch(cB1), (c1 + 2) & 3);
        if (t < 256) { dmaA(pch(cA0), (c0 + 4) & 3); dmaA(pch(cA1), (c1 + 4) & 3); }
        __builtin_amdgcn_sched_barrier(0);
        if (t < 256) { asm volatile("s_waitcnt vmcnt(10)" ::: "memory"); }
        else         { asm volatile("s_waitcnt vmcnt(8)"  ::: "memory"); }
        __builtin_amdgcn_sched_barrier(0);

        // read phase: 16 fragment reads (2 chunks) + 2 convert reads; ONE wait
        const unsigned aB0 = ABF_BASE_B + (unsigned)(c0 & 3) * ABF_ST_B;
        const unsigned aB1 = ABF_BASE_B + (unsigned)(c1 & 3) * ABF_ST_B;
        const unsigned bB0 = B_BASE_B + (unsigned)(c0 & 3) * B_ST_B;
        const unsigned bB1 = B_BASE_B + (unsigned)(c1 & 3) * B_ST_B;
        short8 ah[2][2], al[2][2], bh[2][2], bl[2][2];
        #pragma unroll
        for (int mi = 0; mi < 2; ++mi) {
            ah[0][mi] = lds_read_s8(aB0 + offA[mi]);
            al[0][mi] = lds_read_s8(aB0 + ABF_LO_B + offA[mi]);
            ah[1][mi] = lds_read_s8(aB1 + offA[mi]);
            al[1][mi] = lds_read_s8(aB1 + ABF_LO_B + offA[mi]);
        }
        #pragma unroll
        for (int ni = 0; ni < 2; ++ni) {
            bh[0][ni] = lds_read_s8(bB0 + offB[ni]);
            bl[0][ni] = lds_read_s8(bB0 + B_PLANE_B + offB[ni]);
            bh[1][ni] = lds_read_s8(bB1 + offB[ni]);
            bl[1][ni] = lds_read_s8(bB1 + B_PLANE_B + offB[ni]);
        }
        f32x4 xa0, xa1;
        const bool doCvt = (t < 256) && (W + 1 < NW);
        if (doCvt) {
            xa0 = lds_read_f4((unsigned)((c0 + 2) & 3) * A32_ST_B + myf32);
            xa1 = lds_read_f4((unsigned)((c1 + 2) & 3) * A32_ST_B + myf32);
        }
        asm volatile("s_waitcnt lgkmcnt(0)" ::: "memory");
        __builtin_amdgcn_sched_barrier(0);   // rule #18: nothing hoists above

        // convert next window's A (VALU + ds_write; no extra wait here)
        if (doCvt) { cvtWriteA(xa0, c0 + 2); cvtWriteA(xa1, c1 + 2); }

        __builtin_amdgcn_s_setprio(1);
        #pragma unroll
        for (int p = 0; p < 2; ++p)
            #pragma unroll
            for (int ni = 0; ni < 2; ++ni)
                #pragma unroll
                for (int mi = 0; mi < 2; ++mi) {
                    acc[mi][ni] = __builtin_amdgcn_mfma_f32_16x16x32_bf16(ah[p][mi], bh[p][ni], acc[mi][ni], 0, 0, 0);
                    acc[mi][ni] = __builtin_amdgcn_mfma_f32_16x16x32_bf16(ah[p][mi], bl[p][ni], acc[mi][ni], 0, 0, 0);
                    acc[mi][ni] = __builtin_amdgcn_mfma_f32_16x16x32_bf16(al[p][mi], bh[p][ni], acc[mi][ni], 0, 0, 0);
                }
        __builtin_amdgcn_s_setprio(0);

        asm volatile("s_waitcnt lgkmcnt(0)" ::: "memory");
        __builtin_amdgcn_s_barrier();
    }
    // Deterministic full drain (clamped tail DMAs) before LDS re-aliasing.
    asm volatile("s_waitcnt vmcnt(0) lgkmcnt(0)" ::: "memory");
    __builtin_amdgcn_sched_barrier(0);
    __builtin_amdgcn_s_barrier();

    // ---- epilogue: LDS-transpose bounce, coalesced logits, fused topk ----
    float* Lt = (float*)lds;            // [32][256] fp32 = 32 KB (aliases A region)
    #pragma unroll
    for (int mi = 0; mi < 2; ++mi)
        #pragma unroll
        for (int ni = 0; ni < 2; ++ni)
            #pragma unroll
            for (int r = 0; r < 4; ++r) {
                const int tok = mi * 16 + g4 * 4 + r;       // C/D: row = quad*4+reg
                const int col = w * 32 + ni * 16 + lane16;  // C/D: col = lane&15
                Lt[tok * N_EXP + col] = acc[mi][ni][r];
            }
    __syncthreads();

    // coalesced logits store: 8192 floats = 2048 float4, 4 per thread
    float4*       Lg  = (float4*)(logits + (size_t)tok0 * N_EXP);
    const float4* Lt4 = (const float4*)Lt;
    #pragma unroll
    for (int i = 0; i < 4; ++i) Lg[i * 512 + t] = Lt4[i * 512 + t];

    // topk: wave w handles local tokens w*4 .. w*4+3
    for (int it = 0; it < 4; ++it) {
        const int tk = w * 4 + it;
        const float4 x = ((const float4*)(Lt + tk * N_EXP))[L];
        float sc[4];
        sc[0] = 1.0f / (1.0f + expf(-x.x));
        sc[1] = 1.0f / (1.0f + expf(-x.y));
        sc[2] = 1.0f / (1.0f + expf(-x.z));
        sc[3] = 1.0f / (1.0f + expf(-x.w));

        float v1 = -1.0f, v2 = -1.0f;
        int   i1 = 0,     i2 = 0;
        #pragma unroll
        for (int j = 0; j < 4; ++j) {
            const int idx = L * 4 + j;
            if (sc[j] > v1)      { v2 = v1; i2 = i1; v1 = sc[j]; i1 = idx; }
            else if (sc[j] > v2) { v2 = sc[j]; i2 = idx; }
        }
        // butterfly merge across each 16-lane group (= 64-expert group)
        #pragma unroll
        for (int offx = 1; offx < 16; offx <<= 1) {
            const float ov1 = __shfl_xor(v1, offx);
            const int   oi1 = __shfl_xor(i1, offx);
            const float ov2 = __shfl_xor(v2, offx);
            const int   oi2 = __shfl_xor(i2, offx);
            const bool o1_beats_m1 = (ov1 > v1) || (ov1 == v1 && oi1 < i1);
            if (o1_beats_m1) {
                const bool m1_beats_o2 = (v1 > ov2) || (v1 == ov2 && i1 < oi2);
                const float nv2 = m1_beats_o2 ? v1 : ov2;
                const int   ni2 = m1_beats_o2 ? i1 : oi2;
                v1 = ov1; i1 = oi1; v2 = nv2; i2 = ni2;
            } else {
                const bool o1_beats_m2 = (ov1 > v2) || (ov1 == v2 && oi1 < i2);
                v2 = o1_beats_m2 ? ov1 : v2;
                i2 = o1_beats_m2 ? oi1 : i2;
            }
        }
        float sum = 0.0f;
        #pragma unroll
        for (int g = 0; g < 4; ++g)
            sum += __shfl(v1, g * 16) + __shfl(v2, g * 16);
        const int   src = ((L >> 1) & 3) * 16;
        const float mv1 = __shfl(v1, src);
        const float mv2 = __shfl(v2, src);
        const int   mi1 = __shfl(i1, src);
        const int   mi2 = __shfl(i2, src);
        if (L < 8) {
            const float myv = (L & 1) ? mv2 : mv1;
            const int   myi = (L & 1) ? mi2 : mi1;
            out_idx[(size_t)(tok0 + tk) * 8 + L] = (float)myi;
            out_w  [(size_t)(tok0 + tk) * 8 + L] = myv * (2.5f / (sum + 1e-10f));
        }
    }
}

// ---------------- fallback (ws too small or LDS cap): fp32 VALU path ----------------
constexpr int FBM = 32;
constexpr int FBK = 16;
constexpr int FNC = D_MODEL / FBK;

__global__ __launch_bounds__(256) void gate_gemm_f32(
    const float* __restrict__ H, const float* __restrict__ W,
    float* __restrict__ logits)
{
    __shared__ float As[2][FBK][FBM + 4];
    __shared__ float Bs[2][FBK][N_EXP + 1];
    const int t = threadIdx.x, tx = t & 31, ty = t >> 5;
    const int tok0 = blockIdx.x * FBM, tokA = t >> 2, kqA = t & 3;
    float4 pa, pb[4];
    float acc[4][8];
    #pragma unroll
    for (int i = 0; i < 4; ++i)
        #pragma unroll
        for (int j = 0; j < 8; ++j) acc[i][j] = 0.0f;
    auto issue_loads = [&](int kc) {
        if (t < 128) pa = *(const float4*)(H + (size_t)(tok0 + tokA) * D_MODEL + kc + kqA * 4);
        #pragma unroll
        for (int j = 0; j < 4; ++j) {
            const int flat = t + 256 * j, e = flat >> 2, kq = flat & 3;
            pb[j] = *(const float4*)(W + (size_t)e * D_MODEL + kc + kq * 4);
        }
    };
    auto write_lds = [&](int buf) {
        if (t < 128) {
            As[buf][kqA * 4 + 0][tokA] = pa.x; As[buf][kqA * 4 + 1][tokA] = pa.y;
            As[buf][kqA * 4 + 2][tokA] = pa.z; As[buf][kqA * 4 + 3][tokA] = pa.w;
        }
        #pragma unroll
        for (int j = 0; j < 4; ++j) {
            const int flat = t + 256 * j, e = flat >> 2, kq = flat & 3;
            Bs[buf][kq * 4 + 0][e] = pb[j].x; Bs[buf][kq * 4 + 1][e] = pb[j].y;
            Bs[buf][kq * 4 + 2][e] = pb[j].z; Bs[buf][kq * 4 + 3][e] = pb[j].w;
        }
    };
    issue_loads(0); write_lds(0); __syncthreads();
    for (int c = 0; c < FNC; ++c) {
        const int buf = c & 1;
        if (c + 1 < FNC) issue_loads((c + 1) * FBK);
        #pragma unroll
        for (int k = 0; k < FBK; ++k) {
            const float4 av = *(const float4*)&As[buf][k][ty * 4];
            const float a[4] = {av.x, av.y, av.z, av.w};
            float b[8];
            #pragma unroll
            for (int j = 0; j < 8; ++j) b[j] = Bs[buf][k][tx + 32 * j];
            #pragma unroll
            for (int i = 0; i < 4; ++i)
                #pragma unroll
                for (int j = 0; j < 8; ++j) acc[i][j] = fmaf(a[i], b[j], acc[i][j]);
        }
        if (c + 1 < FNC) write_lds(buf ^ 1);
        __syncthreads();
    }
    #pragma unroll
    for (int i = 0; i < 4; ++i) {
        const size_t row = (size_t)(tok0 + ty * 4 + i) * N_EXP;
        #pragma unroll
        for (int j = 0; j < 8; ++j) logits[row + tx + 32 * j] = acc[i][j];
    }
}

__global__ __launch_bounds__(256) void topk_only(
    const float* __restrict__ logits,
    float* __restrict__ out_idx, float* __restrict__ out_w)
{
    const int token = blockIdx.x * 4 + (threadIdx.x >> 6);
    const int lane  = threadIdx.x & 63;
    const float4 x = *(const float4*)(logits + (size_t)token * N_EXP + lane * 4);
    float sc[4];
    sc[0] = 1.0f / (1.0f + expf(-x.x)); sc[1] = 1.0f / (1.0f + expf(-x.y));
    sc[2] = 1.0f / (1.0f + expf(-x.z)); sc[3] = 1.0f / (1.0f + expf(-x.w));
    float v1 = -1.0f, v2 = -1.0f; int i1 = 0, i2 = 0;
    #pragma unroll
    for (int j = 0; j < 4; ++j) {
        const int idx = lane * 4 + j;
        if (sc[j] > v1)      { v2 = v1; i2 = i1; v1 = sc[j]; i1 = idx; }
        else if (sc[j] > v2) { v2 = sc[j]; i2 = idx; }
    }
    #pragma unroll
    for (int offx = 1; offx < 16; offx <<= 1) {
        const float ov1 = __shfl_xor(v1, offx); const int oi1 = __shfl_xor(i1, offx);
        const float ov2 = __shfl_xor(v2, offx); const int oi2 = __shfl_xor(i2, offx);
        const bool o1_beats_m1 = (ov1 > v1) || (ov1 == v1 && oi1 < i1);
        if (o1_beats_m1) {
            const bool m1_beats_o2 = (v1 > ov2) || (v1 == ov2 && i1 < oi2);
            const float nv2 = m1_beats_o2 ? v1 : ov2;
            const int   ni2 = m1_beats_o2 ? i1 : oi2;
            v1 = ov1; i1 = oi1; v2 = nv2; i2 = ni2;
        } else {
            const bool o1_beats_m2 = (ov1 > v2) || (ov1 == v2 && oi1 < i2);
            v2 = o1_beats_m2 ? ov1 : v2; i2 = o1_beats_m2 ? oi1 : i2;
        }
    }
    float sum = 0.0f;
    #pragma unroll
    for (int g = 0; g < 4; ++g) sum += __shfl(v1, g * 16) + __shfl(v2, g * 16);
    const int src = ((lane >> 1) & 3) * 16;
    const float mv1 = __shfl(v1, src), mv2 = __shfl(v2, src);
    const int   mi1 = __shfl(i1, src), mi2 = __shfl(i2, src);
    if (lane < 8) {
        const float myv = (lane & 1) ? mv2 : mv1;
        const int   myi = (lane & 1) ? mi2 : mi1;
        out_idx[(size_t)token * 8 + lane] = (float)myi;
        out_w  [(size_t)token * 8 + lane] = myv * (2.5f / (sum + 1e-10f));
    }
}

extern "C" void kernel_launch(void* const* d_in, const int* in_sizes, int n_in,
                              void* d_out, int out_size, void* d_ws, size_t ws_size,
                              hipStream_t stream) {
    const float* H = (const float*)d_in[0];   // hidden_states [8192, 4096]
    const float* W = (const float*)d_in[1];   // gate_w        [256, 4096]

    float* out     = (float*)d_out;
    float* out_idx = out;                           // 8192*8
    float* out_w   = out + (size_t)N_TOKENS * 8;    // 8192*8
    float* logits  = out + (size_t)N_TOKENS * 16;   // 8192*256

    static int lds_ok = -1;
    if (lds_ok < 0) {
        hipError_t e = hipFuncSetAttribute((const void*)gate_fused,
                                           hipFuncAttributeMaxDynamicSharedMemorySize,
                                           (int)LDS_BYTES);
        lds_ok = (e == hipSuccess) ? 1 : 0;
    }

    if (ws_size >= WS_NEED && lds_ok == 1) {
        unsigned short* wsB = (unsigned short*)d_ws;
        convert_w<<<dim3(NC * 4), dim3(256), 0, stream>>>(W, wsB);
        gate_fused<<<dim3(N_TOKENS / BM), dim3(512), LDS_BYTES, stream>>>(
            H, wsB, logits, out_idx, out_w);
    } else {
        gate_gemm_f32<<<dim3(N_TOKENS / FBM), dim3(256), 0, stream>>>(H, W, logits);
        topk_only<<<dim3(N_TOKENS / 4), dim3(256), 0, stream>>>(logits, out_idx, out_w);
    }
}